// Round 6
// baseline (578.312 us; speedup 1.0000x reference)
//
#include <hip/hip_runtime.h>

// ---------------------------------------------------------------------------
// InvariantPolynomial, round 8: k_out via per-(src, z_dst) linear tables.
//
// Round-7 post-mortem: src-major k_out killed the gather (FETCH 215->18MB)
// but the per-edge 7x6-step shuffle reduce + serial atomics cost ~150
// wave-instr/edge -> 228us, VALU-issue-bound.
//
// Fix (algebra): per edge, out contribution = P_{src,q} . [1,B1,B2] (7x9
// linear map). q = 4 z[src]+z[dst], z[src] fixed per src -> only 4 tables
// x 62 floats per node. Precompute = contraction of mid row with w2
// (~5.8K madds/node, done once per node in LDS). Edge phase: ONE THREAD
// PER EDGE: 62 LDS reads (broadcast-heavy), ~60 FMA, one pos4[dst] 16B
// gather (batch packed in pos4.w), 7 per-lane atomics. No wave reduce.
//
// ws layout (ints/floats):
//   counts  @ int   [0      , 20000)
//   start   @ int   [32768  , 52769)
//   cursor  @ int   [65536  , 85536)
//   csr     @ int   [98304  , 418304)   dst-CSR, then src-CSR after k_fill2
//   pos4    @ float [425984 , 505984)   20000 x 4 (w = batch bits)
//   node_sh @ float [524288 , 764288)   20000 x 12 (9 used, inv_nn folded)
//   counts2 @ int   [770048 , 790048)
//   start2  @ int   [790528 , 810529)
//   cursor2 @ int   [811008 , 831008)
//   mid     @ float [1048576, 8408576)  20000 x 368
// ---------------------------------------------------------------------------

#define N_EDGES   320000
#define NN_NODES  20000
#define NN_GRAPHS 5000

__device__ __forceinline__ void sh_from_vec(float x, float y, float z,
                                            float* B1, float* B2) {
    const float s3   = 1.7320508075688772f;
    const float s15  = 3.8729833462074170f;
    const float s5h  = 1.1180339887498949f;
    const float s15h = 1.9364916731037085f;
    B1[0] = s3 * y; B1[1] = s3 * z; B1[2] = s3 * x;
    float r2 = x * x + y * y + z * z;
    B2[0] = s15 * x * y;
    B2[1] = s15 * y * z;
    B2[2] = s5h * (3.f * z * z - r2);
    B2[3] = s15 * x * z;
    B2[4] = s15h * (x * x - y * y);
}

// --------------------------- zero + pos4 pack (batch in .w) ----------------
__global__ __launch_bounds__(256) void k_zero(const float* __restrict__ pos,
                                              const int* __restrict__ batch,
                                              int* __restrict__ counts,
                                              int* __restrict__ counts2,
                                              float* __restrict__ out,
                                              float4* __restrict__ pos4) {
    int tid = blockIdx.x * blockDim.x + threadIdx.x;
    int stride = gridDim.x * blockDim.x;
    for (int i = tid; i < NN_NODES; i += stride) { counts[i] = 0; counts2[i] = 0; }
    for (int i = tid; i < NN_GRAPHS * 7; i += stride) out[i] = 0.f;
    for (int i = tid; i < NN_NODES; i += stride) {
        float4 p;
        p.x = pos[3 * i]; p.y = pos[3 * i + 1]; p.z = pos[3 * i + 2];
        p.w = __int_as_float(batch[i]);
        pos4[i] = p;
    }
}

// --------------------------- histogram (both endpoints) --------------------
__global__ __launch_bounds__(256) void k_hist(const int* __restrict__ esrc,
                                              const int* __restrict__ edst,
                                              int* __restrict__ counts,
                                              int* __restrict__ counts2) {
    int e = blockIdx.x * blockDim.x + threadIdx.x;
    if (e < N_EDGES) {
        atomicAdd(&counts[edst[e]], 1);
        atomicAdd(&counts2[esrc[e]], 1);
    }
}

// ----------------- dual exclusive scan (1 block of 1024) -------------------
__global__ __launch_bounds__(1024) void k_scan2(const int* __restrict__ counts,
                                                const int* __restrict__ counts2,
                                                int* __restrict__ start,
                                                int* __restrict__ cursor,
                                                int* __restrict__ start2,
                                                int* __restrict__ cursor2) {
    __shared__ int sa[1024];
    __shared__ int sb[1024];
    __shared__ int carryA, carryB;
    int tid = threadIdx.x;
    if (tid == 0) { carryA = 0; carryB = 0; }
    __syncthreads();
    for (int base = 0; base < NN_NODES; base += 1024) {
        int i = base + tid;
        int va = (i < NN_NODES) ? counts[i] : 0;
        int vb = (i < NN_NODES) ? counts2[i] : 0;
        sa[tid] = va; sb[tid] = vb;
        __syncthreads();
        for (int off = 1; off < 1024; off <<= 1) {
            int ta = (tid >= off) ? sa[tid - off] : 0;
            int tb = (tid >= off) ? sb[tid - off] : 0;
            __syncthreads();
            sa[tid] += ta; sb[tid] += tb;
            __syncthreads();
        }
        int cA = carryA, cB = carryB;
        if (i < NN_NODES) {
            int ea = cA + sa[tid] - va;
            int eb = cB + sb[tid] - vb;
            start[i] = ea;  cursor[i] = ea;
            start2[i] = eb; cursor2[i] = eb;
        }
        __syncthreads();
        if (tid == 0) { carryA = cA + sa[1023]; carryB = cB + sb[1023]; }
        __syncthreads();
    }
    if (tid == 0) { start[NN_NODES] = carryA; start2[NN_NODES] = carryB; }
}

// --------------------------- dst-CSR fill ----------------------------------
__global__ __launch_bounds__(256) void k_fill(const int* __restrict__ esrc,
                                              const int* __restrict__ edst,
                                              const int* __restrict__ zarr,
                                              int* __restrict__ cursor,
                                              int* __restrict__ csr) {
    int e = blockIdx.x * blockDim.x + threadIdx.x;
    if (e >= N_EDGES) return;
    int d = edst[e];
    int s = esrc[e];
    int q = 4 * zarr[s] + zarr[d];
    int p = atomicAdd(&cursor[d], 1);
    csr[p] = s | (q << 16) | ((d & 15) << 20);
}

// --------------------------- src-CSR fill (overwrites csr) -----------------
// word: d (15b) | z[d] (2b @15) | (s&15) (4b @17)
__global__ __launch_bounds__(256) void k_fill2(const int* __restrict__ esrc,
                                               const int* __restrict__ edst,
                                               const int* __restrict__ zarr,
                                               int* __restrict__ cursor2,
                                               int* __restrict__ csr) {
    int e = blockIdx.x * blockDim.x + threadIdx.x;
    if (e >= N_EDGES) return;
    int d = edst[e];
    int s = esrc[e];
    int p = atomicAdd(&cursor2[s], 1);
    csr[p] = d | (zarr[d] << 15) | ((s & 15) << 17);
}

// ------------------- node_sh: edge-parallel, 16 nodes/block ----------------
__global__ __launch_bounds__(256) void k_nodesh(const float4* __restrict__ pos4,
                                                const int* __restrict__ start,
                                                const int* __restrict__ csr,
                                                float* __restrict__ node_sh) {
    __shared__ float ns[16][12];
    int t = threadIdx.x;
    if (t < 192) ns[t / 12][t % 12] = 0.f;
    __syncthreads();
    int nbase = blockIdx.x * 16;
    int e0 = start[nbase], e1 = start[nbase + 16];
    for (int idx = e0 + t; idx < e1; idx += 256) {
        int pk = csr[idx];
        int s = pk & 0xFFFF;
        int r = (pk >> 20) & 15;
        float4 pd = pos4[nbase + r];
        float4 ps = pos4[s];
        float x = ps.x - pd.x;
        float y = ps.y - pd.y;
        float z = ps.z - pd.z;
        float B1[3], B2[5];
        sh_from_vec(x, y, z, B1, B2);
        float* nr = &ns[r][0];
        atomicAdd(nr + 0, 1.f);
        atomicAdd(nr + 1, B1[0]); atomicAdd(nr + 2, B1[1]); atomicAdd(nr + 3, B1[2]);
        atomicAdd(nr + 4, B2[0]); atomicAdd(nr + 5, B2[1]); atomicAdd(nr + 6, B2[2]);
        atomicAdd(nr + 7, B2[3]); atomicAdd(nr + 8, B2[4]);
    }
    __syncthreads();
    if (t < 144) {
        int r = t / 9, c = t % 9;
        const float inv_nn = 0.57735026918962576f;
        node_sh[(size_t)(nbase + r) * 12 + c] = ns[r][c] * inv_nn;
    }
}

// --------------- fused TP1: G in LDS -> W1 contraction -> mid --------------
// (unchanged from round 6/7)
__global__ __launch_bounds__(512, 6) void k_mid(const float4* __restrict__ pos4,
                                                const float* __restrict__ node_sh,
                                                const int* __restrict__ start,
                                                const int* __restrict__ csr,
                                                const float* __restrict__ w1,
                                                float* __restrict__ mid) {
    __shared__ float Gl[8 * 816];
    int t = threadIdx.x;
    for (int i = t; i < 8 * 816; i += 512) Gl[i] = 0.f;
    __syncthreads();

    int nbase = blockIdx.x * 8;
    int e0 = start[nbase], e1 = start[nbase + 8];

    const float r3  = 0.57735026918962576f;
    const float r5  = 0.44721359549995794f;
    const float r6  = 0.40824829046386302f;
    const float r10 = 0.31622776601683794f;
    const float s30 = 0.18257418583505536f;
    const float rt3 = 1.7320508075688772f;
    const float c222 = 0.58554004376911990f;
    const float q6 = 0.40824829046386302f;
    const float h6 = 0.20412414523193151f;
    const float h2 = 0.35355339059327376f;
    const float r2c = 0.70710678118654752f;

    for (int idx = e0 + t; idx < e1; idx += 512) {
        int pk = csr[idx];
        int s = pk & 0xFFFF;
        int q = (pk >> 16) & 15;
        int r = (pk >> 20) & 7;
        float4 pd = pos4[nbase + r];
        float4 ps = pos4[s];
        float x = ps.x - pd.x;
        float y = ps.y - pd.y;
        float z = ps.z - pd.z;
        float B1[3], B2[5];
        sh_from_vec(x, y, z, B1, B2);
        const float4 nv0 = *(const float4*)(node_sh + s * 12);
        const float4 nv1 = *(const float4*)(node_sh + s * 12 + 4);
        float a0 = nv0.x;
        float A1[3] = {nv0.y, nv0.z, nv0.w};
        float A2[5] = {nv1.x, nv1.y, nv1.z, nv1.w, node_sh[s * 12 + 8]};
        float* gr = Gl + r * 816 + q * 51;

        atomicAdd(gr + 0, a0);
        atomicAdd(gr + 1, a0 * B1[0] * r3);
        atomicAdd(gr + 2, a0 * B1[1] * r3);
        atomicAdd(gr + 3, a0 * B1[2] * r3);
        atomicAdd(gr + 4, a0 * B2[0] * r5);
        atomicAdd(gr + 5, a0 * B2[1] * r5);
        atomicAdd(gr + 6, a0 * B2[2] * r5);
        atomicAdd(gr + 7, a0 * B2[3] * r5);
        atomicAdd(gr + 8, a0 * B2[4] * r5);
        atomicAdd(gr + 9,  A1[0] * r3);
        atomicAdd(gr + 10, A1[1] * r3);
        atomicAdd(gr + 11, A1[2] * r3);
        atomicAdd(gr + 12, -r3 * (A1[0] * B1[0] + A1[1] * B1[1] + A1[2] * B1[2]));
        atomicAdd(gr + 13, -r6 * (A1[1] * B1[2] - A1[2] * B1[1]));
        atomicAdd(gr + 14, -r6 * (A1[2] * B1[0] - A1[0] * B1[2]));
        atomicAdd(gr + 15, -r6 * (A1[0] * B1[1] - A1[1] * B1[0]));
        atomicAdd(gr + 16, r10 * (A1[0] * B1[2] + A1[2] * B1[0]));
        atomicAdd(gr + 17, r10 * (A1[0] * B1[1] + A1[1] * B1[0]));
        atomicAdd(gr + 18, s30 * (2.f * A1[1] * B1[1] - A1[0] * B1[0] - A1[2] * B1[2]));
        atomicAdd(gr + 19, r10 * (A1[1] * B1[2] + A1[2] * B1[1]));
        atomicAdd(gr + 20, r10 * (A1[2] * B1[2] - A1[0] * B1[0]));
        {
            float Byy = -B2[2] * q6 - B2[4] * r2c;
            float Bzz = 2.f * B2[2] * q6;
            float Bxx = -B2[2] * q6 + B2[4] * r2c;
            float Bxy = B2[0] * r2c;
            float Byz = B2[1] * r2c;
            float Bxz = B2[3] * r2c;
            atomicAdd(gr + 21, -r5 * (Byy * A1[0] + Byz * A1[1] + Bxy * A1[2]));
            atomicAdd(gr + 22, -r5 * (Byz * A1[0] + Bzz * A1[1] + Bxz * A1[2]));
            atomicAdd(gr + 23, -r5 * (Bxy * A1[0] + Bxz * A1[1] + Bxx * A1[2]));
        }
        atomicAdd(gr + 24, -s30 * (B2[1] * A1[0] - B2[3] * A1[2] + 2.f * B2[4] * A1[1]));
        atomicAdd(gr + 25, -s30 * (-B2[0] * A1[0] - rt3 * B2[2] * A1[2] + B2[3] * A1[1] - B2[4] * A1[2]));
        atomicAdd(gr + 26, -s30 * (rt3 * B2[1] * A1[2] - rt3 * B2[3] * A1[0]));
        atomicAdd(gr + 27, -s30 * (B2[0] * A1[2] - B2[1] * A1[1] + rt3 * B2[2] * A1[0] - B2[4] * A1[0]));
        atomicAdd(gr + 28, -s30 * (-2.f * B2[0] * A1[1] + B2[1] * A1[2] + B2[3] * A1[0]));
        atomicAdd(gr + 29, A2[0] * r5);
        atomicAdd(gr + 30, A2[1] * r5);
        atomicAdd(gr + 31, A2[2] * r5);
        atomicAdd(gr + 32, A2[3] * r5);
        atomicAdd(gr + 33, A2[4] * r5);
        {
            float Ayy = -A2[2] * q6 - A2[4] * r2c;
            float Azz = 2.f * A2[2] * q6;
            float Axx = -A2[2] * q6 + A2[4] * r2c;
            float Axy = A2[0] * r2c;
            float Ayz = A2[1] * r2c;
            float Axz = A2[3] * r2c;
            atomicAdd(gr + 34, -r5 * (Ayy * B1[0] + Ayz * B1[1] + Axy * B1[2]));
            atomicAdd(gr + 35, -r5 * (Ayz * B1[0] + Azz * B1[1] + Axz * B1[2]));
            atomicAdd(gr + 36, -r5 * (Axy * B1[0] + Axz * B1[1] + Axx * B1[2]));
        }
        atomicAdd(gr + 37, s30 * (A2[1] * B1[0] - A2[3] * B1[2] + 2.f * A2[4] * B1[1]));
        atomicAdd(gr + 38, s30 * (-A2[0] * B1[0] - rt3 * A2[2] * B1[2] + A2[3] * B1[1] - A2[4] * B1[2]));
        atomicAdd(gr + 39, s30 * (rt3 * A2[1] * B1[2] - rt3 * A2[3] * B1[0]));
        atomicAdd(gr + 40, s30 * (A2[0] * B1[2] - A2[1] * B1[1] + rt3 * A2[2] * B1[0] - A2[4] * B1[0]));
        atomicAdd(gr + 41, s30 * (-2.f * A2[0] * B1[1] + A2[1] * B1[2] + A2[3] * B1[0]));
        atomicAdd(gr + 42, r5 * (A2[0] * B2[0] + A2[1] * B2[1] + A2[2] * B2[2] +
                                 A2[3] * B2[3] + A2[4] * B2[4]));
        atomicAdd(gr + 43, s30 * (-A2[0] * B2[1] + A2[1] * B2[0] +
                                  rt3 * (A2[2] * B2[3] - A2[3] * B2[2]) +
                                  A2[3] * B2[4] - A2[4] * B2[3]));
        atomicAdd(gr + 44, s30 * (-2.f * A2[0] * B2[4] + 2.f * A2[4] * B2[0] -
                                  A2[1] * B2[3] + A2[3] * B2[1]));
        atomicAdd(gr + 45, s30 * (A2[0] * B2[3] - A2[3] * B2[0] +
                                  rt3 * (A2[1] * B2[2] - A2[2] * B2[1]) +
                                  A2[1] * B2[4] - A2[4] * B2[1]));
        atomicAdd(gr + 46, -c222 * (-q6 * (A2[0] * B2[2] + A2[2] * B2[0]) +
                                    h2 * (A2[1] * B2[3] + A2[3] * B2[1])));
        atomicAdd(gr + 47, -c222 * (h6 * (A2[1] * B2[2] + A2[2] * B2[1]) -
                                    h2 * (A2[1] * B2[4] + A2[4] * B2[1]) +
                                    h2 * (A2[0] * B2[3] + A2[3] * B2[0])));
        atomicAdd(gr + 48, -c222 * (q6 * (A2[2] * B2[2] - A2[0] * B2[0] - A2[4] * B2[4]) +
                                    h6 * (A2[1] * B2[1] + A2[3] * B2[3])));
        atomicAdd(gr + 49, -c222 * (h6 * (A2[3] * B2[2] + A2[2] * B2[3]) +
                                    h2 * (A2[3] * B2[4] + A2[4] * B2[3]) +
                                    h2 * (A2[0] * B2[1] + A2[1] * B2[0])));
        atomicAdd(gr + 50, -c222 * (-q6 * (A2[4] * B2[2] + A2[2] * B2[4]) +
                                    h2 * (A2[3] * B2[3] - A2[1] * B2[1])));
    }
    __syncthreads();

    // Phase 2: q-outer, acc[8] (static unroll), weights from global w1.
    int j = t;
    if (j >= 368) return;
    float acc[8] = {0.f, 0.f, 0.f, 0.f, 0.f, 0.f, 0.f, 0.f};
    if (j < 64) {
        int w = j;
        for (int q = 0; q < 16; q++) {
            float wa = w1[q * 64 + w];
            float wb = w1[2048 + q * 64 + w];
            float wc = w1[5248 + q * 64 + w];
            const float* Gq = Gl + q * 51;
#pragma unroll
            for (int r2 = 0; r2 < 8; r2++) {
                const float* gq = Gq + r2 * 816;
                acc[r2] += gq[0] * wa + gq[12] * wb + gq[42] * wc;
            }
        }
#pragma unroll
        for (int r2 = 0; r2 < 8; r2++)
            mid[(size_t)(nbase + r2) * 368 + j] = 0.33333333333333333f * acc[r2];
    } else if (j < 136) {
        int tt = j - 64, w = tt / 3, k = tt - 3 * w;
        for (int q = 0; q < 16; q++) {
            float wa = w1[3072 + q * 24 + w];
            float wb = w1[6272 + q * 24 + w];
            const float* Gq = Gl + q * 51;
#pragma unroll
            for (int r2 = 0; r2 < 8; r2++) {
                const float* gq = Gq + r2 * 816;
                acc[r2] += gq[13 + k] * wa + gq[43 + k] * wb;
            }
        }
#pragma unroll
        for (int r2 = 0; r2 < 8; r2++)
            mid[(size_t)(nbase + r2) * 368 + j] = 0.70710678118654752f * acc[r2];
    } else if (j < 208) {
        int tt = j - 136, w = tt / 3, k = tt - 3 * w;
        for (int q = 0; q < 16; q++) {
            float wa = w1[1024 + q * 24 + w];
            float wb = w1[1664 + q * 24 + w];
            float wc = w1[3712 + q * 24 + w];
            float wd = w1[4608 + q * 24 + w];
            const float* Gq = Gl + q * 51;
#pragma unroll
            for (int r2 = 0; r2 < 8; r2++) {
                const float* gq = Gq + r2 * 816;
                acc[r2] += gq[1 + k] * wa + gq[9 + k] * wb +
                           gq[21 + k] * wc + gq[34 + k] * wd;
            }
        }
#pragma unroll
        for (int r2 = 0; r2 < 8; r2++)
            mid[(size_t)(nbase + r2) * 368 + j] = 0.5f * acc[r2];
    } else if (j < 288) {
        int tt = j - 208, w = tt / 5, k = tt - 5 * w;
        for (int q = 0; q < 16; q++) {
            float wa = w1[1408 + q * 16 + w];
            float wb = w1[3456 + q * 16 + w];
            float wc = w1[4352 + q * 16 + w];
            float wd = w1[6656 + q * 16 + w];
            const float* Gq = Gl + q * 51;
#pragma unroll
            for (int r2 = 0; r2 < 8; r2++) {
                const float* gq = Gq + r2 * 816;
                acc[r2] += gq[4 + k] * wa + gq[16 + k] * wb +
                           gq[29 + k] * wc + gq[46 + k] * wd;
            }
        }
#pragma unroll
        for (int r2 = 0; r2 < 8; r2++)
            mid[(size_t)(nbase + r2) * 368 + j] = 0.64549722436790280f * acc[r2];
    } else {
        int tt = j - 288, w = tt / 5, k = tt - 5 * w;
        for (int q = 0; q < 16; q++) {
            float wa = w1[4096 + q * 16 + w];
            float wb = w1[4992 + q * 16 + w];
            const float* Gq = Gl + q * 51;
#pragma unroll
            for (int r2 = 0; r2 < 8; r2++) {
                const float* gq = Gq + r2 * 816;
                acc[r2] += gq[24 + k] * wa + gq[37 + k] * wb;
            }
        }
#pragma unroll
        for (int r2 = 0; r2 < 8; r2++)
            mid[(size_t)(nbase + r2) * 368 + j] = 0.91287092917527690f * acc[r2];
    }
}

// -------- TP2 + graph reduce via per-(src, z_dst) 62-float tables ----------
// 256 thr / 16 src nodes / block. Phase A: stage mid rows + build tables.
// Phase B: one THREAD per edge: o[7] = P.[1,B1,B2], 7 per-lane atomics.
// Table layout per (r,zd), stride 65:
//   [0..5]  P0[w]      (T0, const term)
//   [6..8]  P1[c]      (T1 -> o0, B1 coeffs)
//   [9..26] P2[c*6+w]  (T2 -> o[w], B1 coeffs)
//   [27..56]P3[c*6+w]  (T3 -> o[w], B2 coeffs)
//   [57..61]P4[c]      (T4 -> o0, B2 coeffs)
__global__ __launch_bounds__(256) void k_out(const float4* __restrict__ pos4,
                                             const int* __restrict__ zarr,
                                             const int* __restrict__ start2,
                                             const int* __restrict__ csr2,
                                             const float* __restrict__ mid,
                                             const float* __restrict__ w2,
                                             float* __restrict__ out) {
    __shared__ float tab[16 * 4 * 65];     // 16.6 KB
    __shared__ float smid[16][368];        // 23.5 KB
    __shared__ float4 spos[16];
    __shared__ int szs[16];

    int tid = threadIdx.x;
    int nbase = blockIdx.x * 16;

    // ---- stage mid rows + pos + z ----
    for (int i = tid; i < 16 * 368; i += 256) {
        int r = i / 368, c = i - r * 368;
        smid[r][c] = mid[(size_t)(nbase + r) * 368 + c];
    }
    if (tid < 16) {
        spos[tid] = pos4[nbase + tid];
        szs[tid] = zarr[nbase + tid];
    }
    __syncthreads();

    const float cT0f =  0.02830690f;
    const float cT1f = -0.02635231f;
    const float cT2f = -0.01634300f;
    const float cT3f =  0.01265893f;
    const float cT4f =  0.02041241f;

    // ---- build tables: 16 nodes x 4 zd x 62 entries ----
    for (int i = tid; i < 16 * 4 * 62; i += 256) {
        int rz = i / 62;
        int j  = i - rz * 62;
        int r  = rz >> 2;
        int zd = rz & 3;
        int q  = 4 * szs[r] + zd;
        const float* mr = &smid[r][0];
        float s = 0.f;
        if (j < 6) {                       // P0[w]: sum_u m[u]*W0[u,q,w]
            int w = j;
            for (int u = 0; u < 64; u++)
                s += mr[u] * w2[(u * 16 + q) * 6 + w];
            s *= cT0f;
        } else if (j < 9) {                // P1[c]: sum_u m[64+3u+c]*W1t[u,q]
            int c = j - 6;
            for (int u = 0; u < 24; u++)
                s += mr[64 + 3 * u + c] * w2[6144 + u * 16 + q];
            s *= cT1f;
        } else if (j < 27) {               // P2[c][w]
            int c = (j - 9) / 6, w = (j - 9) % 6;
            for (int u = 0; u < 24; u++)
                s += mr[136 + 3 * u + c] * w2[6528 + (u * 16 + q) * 6 + w];
            s *= cT2f;
        } else if (j < 57) {               // P3[c][w]
            int c = (j - 27) / 6, w = (j - 27) % 6;
            for (int u = 0; u < 16; u++)
                s += mr[208 + 5 * u + c] * w2[8832 + (u * 16 + q) * 6 + w];
            s *= cT3f;
        } else {                           // P4[c]
            int c = j - 57;
            for (int u = 0; u < 16; u++)
                s += mr[288 + 5 * u + c] * w2[10368 + u * 16 + q];
            s *= cT4f;
        }
        tab[rz * 65 + j] = s;
    }
    __syncthreads();

    // ---- edge phase: one thread per edge ----
    int e0 = start2[nbase], e1 = start2[nbase + 16];
    for (int idx = e0 + tid; idx < e1; idx += 256) {
        int pk = csr2[idx];
        int d  = pk & 0x7FFF;
        int zd = (pk >> 15) & 3;
        int r  = (pk >> 17) & 15;
        float4 pb = pos4[d];
        int b = __float_as_int(pb.w);
        float4 sp = spos[r];
        float x = sp.x - pb.x;
        float y = sp.y - pb.y;
        float z = sp.z - pb.z;
        float B1[3], B2[5];
        sh_from_vec(x, y, z, B1, B2);

        const float* T = &tab[(r * 4 + zd) * 65];
        float o0 = T[6] * B1[0] + T[7] * B1[1] + T[8] * B1[2]
                 + T[57] * B2[0] + T[58] * B2[1] + T[59] * B2[2]
                 + T[60] * B2[3] + T[61] * B2[4];
        float* og = out + b * 7;
        atomicAdd(og, o0);
#pragma unroll
        for (int w = 0; w < 6; w++) {
            float ow = T[w]
                     + B1[0] * T[9 + w]  + B1[1] * T[15 + w] + B1[2] * T[21 + w]
                     + B2[0] * T[27 + w] + B2[1] * T[33 + w] + B2[2] * T[39 + w]
                     + B2[3] * T[45 + w] + B2[4] * T[51 + w];
            atomicAdd(og + 1 + w, ow);
        }
    }
}

// ---------------------------------------------------------------------------
extern "C" void kernel_launch(void* const* d_in, const int* in_sizes, int n_in,
                              void* d_out, int out_size, void* d_ws, size_t ws_size,
                              hipStream_t stream) {
    const float* pos  = (const float*)d_in[0];
    const int*   z    = (const int*)d_in[1];
    const int*   bat  = (const int*)d_in[2];
    const int*   esrc = (const int*)d_in[3];
    const int*   edst = (const int*)d_in[4];
    const float* w1   = (const float*)d_in[5];
    const float* w2   = (const float*)d_in[6];
    float* out = (float*)d_out;

    int*   wsI = (int*)d_ws;
    float* wsF = (float*)d_ws;
    int* counts  = wsI + 0;
    int* start   = wsI + 32768;
    int* cursor  = wsI + 65536;
    int* csr     = wsI + 98304;
    float4* pos4   = (float4*)(wsF + 425984);
    float* node_sh = wsF + 524288;
    int* counts2 = wsI + 770048;
    int* start2  = wsI + 790528;
    int* cursor2 = wsI + 811008;
    float* mid     = wsF + 1048576;

    k_zero<<<64, 256, 0, stream>>>(pos, bat, counts, counts2, out, pos4);
    k_hist<<<(N_EDGES + 255) / 256, 256, 0, stream>>>(esrc, edst, counts, counts2);
    k_scan2<<<1, 1024, 0, stream>>>(counts, counts2, start, cursor, start2, cursor2);
    k_fill<<<(N_EDGES + 255) / 256, 256, 0, stream>>>(esrc, edst, z, cursor, csr);
    k_nodesh<<<NN_NODES / 16, 256, 0, stream>>>(pos4, start, csr, node_sh);
    k_mid<<<NN_NODES / 8, 512, 0, stream>>>(pos4, node_sh, start, csr, w1, mid);
    k_fill2<<<(N_EDGES + 255) / 256, 256, 0, stream>>>(esrc, edst, z, cursor2, csr);
    k_out<<<NN_NODES / 16, 256, 0, stream>>>(pos4, z, start2, csr, mid, w2, out);
}

// Round 7
// 527.880 us; speedup vs baseline: 1.0955x; 1.0955x over previous
//
#include <hip/hip_runtime.h>

// ---------------------------------------------------------------------------
// InvariantPolynomial, round 9: dst-major k_out over per-(src,z_dst) tables.
//
// Round-8 post-mortem: rounds 7 AND 8 (totally different k_out structures)
// both ran 228.7us with WRITE_SIZE=70MB: the shared 2.24M global atomics
// (7/edge, 64 RMW/address) are the wall. Fix: reduce per NODE, not per edge.
//
//  * k_mid: phase 3 fused -- mid row (LDS) x w2 -> tab[node][zd][64]
//    (padded, pad zeroed). Global mid eliminated entirely.
//  * k_out: dst-major, wave/node: per edge ONE coalesced 248B tab-row load,
//    factor via 9 per-lane 0/1 mask-FMAs, acc += T*factor. Segmented 7-way
//    reduce ONCE per node -> 7 atomics/node (140K total, 16x fewer).
//  * src-CSR infra (fill2/dual hist/dual scan) deleted.
//
// ws layout (ints/floats):
//   counts  @ int   [0      , 20000)
//   start   @ int   [32768  , 52769)
//   cursor  @ int   [65536  , 85536)
//   csr     @ int   [98304  , 418304)   dst-CSR: s | q<<16 | (d&15)<<20
//   pos4    @ float [425984 , 505984)   20000 x 4
//   node_sh @ float [524288 , 764288)   20000 x 12 (9 used, inv_nn folded)
//   tab     @ float [1048576, 6168576)  20000 x 4 x 64
// ---------------------------------------------------------------------------

#define N_EDGES   320000
#define NN_NODES  20000
#define NN_GRAPHS 5000

__device__ __forceinline__ void sh_from_vec(float x, float y, float z,
                                            float* B1, float* B2) {
    const float s3   = 1.7320508075688772f;
    const float s15  = 3.8729833462074170f;
    const float s5h  = 1.1180339887498949f;
    const float s15h = 1.9364916731037085f;
    B1[0] = s3 * y; B1[1] = s3 * z; B1[2] = s3 * x;
    float r2 = x * x + y * y + z * z;
    B2[0] = s15 * x * y;
    B2[1] = s15 * y * z;
    B2[2] = s5h * (3.f * z * z - r2);
    B2[3] = s15 * x * z;
    B2[4] = s15h * (x * x - y * y);
}

// --------------------------- zero + pos4 pack ------------------------------
__global__ __launch_bounds__(256) void k_zero(const float* __restrict__ pos,
                                              int* __restrict__ counts,
                                              float* __restrict__ out,
                                              float4* __restrict__ pos4) {
    int tid = blockIdx.x * blockDim.x + threadIdx.x;
    int stride = gridDim.x * blockDim.x;
    for (int i = tid; i < NN_NODES; i += stride) counts[i] = 0;
    for (int i = tid; i < NN_GRAPHS * 7; i += stride) out[i] = 0.f;
    for (int i = tid; i < NN_NODES; i += stride) {
        float4 p;
        p.x = pos[3 * i]; p.y = pos[3 * i + 1]; p.z = pos[3 * i + 2]; p.w = 0.f;
        pos4[i] = p;
    }
}

// --------------------------- histogram -------------------------------------
__global__ __launch_bounds__(256) void k_hist(const int* __restrict__ edst,
                                              int* __restrict__ counts) {
    int e = blockIdx.x * blockDim.x + threadIdx.x;
    if (e < N_EDGES) atomicAdd(&counts[edst[e]], 1);
}

// --------------------------- exclusive scan (1 block of 1024) --------------
__global__ __launch_bounds__(1024) void k_scan(const int* __restrict__ counts,
                                               int* __restrict__ start,
                                               int* __restrict__ cursor) {
    __shared__ int sdata[1024];
    __shared__ int carry;
    int tid = threadIdx.x;
    if (tid == 0) carry = 0;
    __syncthreads();
    for (int base = 0; base < NN_NODES; base += 1024) {
        int i = base + tid;
        int v = (i < NN_NODES) ? counts[i] : 0;
        sdata[tid] = v;
        __syncthreads();
        for (int off = 1; off < 1024; off <<= 1) {
            int t = (tid >= off) ? sdata[tid - off] : 0;
            __syncthreads();
            sdata[tid] += t;
            __syncthreads();
        }
        int incl = sdata[tid];
        int c = carry;
        if (i < NN_NODES) {
            int excl = c + incl - v;
            start[i] = excl;
            cursor[i] = excl;
        }
        __syncthreads();
        if (tid == 0) carry = c + sdata[1023];
        __syncthreads();
    }
    if (tid == 0) start[NN_NODES] = carry;   // = N_EDGES
}

// --------------------------- dst-CSR fill ----------------------------------
__global__ __launch_bounds__(256) void k_fill(const int* __restrict__ esrc,
                                              const int* __restrict__ edst,
                                              const int* __restrict__ zarr,
                                              int* __restrict__ cursor,
                                              int* __restrict__ csr) {
    int e = blockIdx.x * blockDim.x + threadIdx.x;
    if (e >= N_EDGES) return;
    int d = edst[e];
    int s = esrc[e];
    int q = 4 * zarr[s] + zarr[d];
    int p = atomicAdd(&cursor[d], 1);
    csr[p] = s | (q << 16) | ((d & 15) << 20);
}

// ------------------- node_sh: edge-parallel, 16 nodes/block ----------------
__global__ __launch_bounds__(256) void k_nodesh(const float4* __restrict__ pos4,
                                                const int* __restrict__ start,
                                                const int* __restrict__ csr,
                                                float* __restrict__ node_sh) {
    __shared__ float ns[16][12];
    int t = threadIdx.x;
    if (t < 192) ns[t / 12][t % 12] = 0.f;
    __syncthreads();
    int nbase = blockIdx.x * 16;
    int e0 = start[nbase], e1 = start[nbase + 16];
    for (int idx = e0 + t; idx < e1; idx += 256) {
        int pk = csr[idx];
        int s = pk & 0xFFFF;
        int r = (pk >> 20) & 15;
        float4 pd = pos4[nbase + r];
        float4 ps = pos4[s];
        float x = ps.x - pd.x;
        float y = ps.y - pd.y;
        float z = ps.z - pd.z;
        float B1[3], B2[5];
        sh_from_vec(x, y, z, B1, B2);
        float* nr = &ns[r][0];
        atomicAdd(nr + 0, 1.f);
        atomicAdd(nr + 1, B1[0]); atomicAdd(nr + 2, B1[1]); atomicAdd(nr + 3, B1[2]);
        atomicAdd(nr + 4, B2[0]); atomicAdd(nr + 5, B2[1]); atomicAdd(nr + 6, B2[2]);
        atomicAdd(nr + 7, B2[3]); atomicAdd(nr + 8, B2[4]);
    }
    __syncthreads();
    if (t < 144) {
        int r = t / 9, c = t % 9;
        const float inv_nn = 0.57735026918962576f;
        node_sh[(size_t)(nbase + r) * 12 + c] = ns[r][c] * inv_nn;
    }
}

// ------- fused TP1 -> mid (LDS only) -> TP2 tables tab[node][zd][64] -------
// 512 threads, 8 nodes/block. Phase 1: edge-parallel G accumulation (LDS).
// Phase 2: mid row into smid (LDS). Phase 3: contract smid x w2 -> tab.
__global__ __launch_bounds__(512, 6) void k_mid(const float4* __restrict__ pos4,
                                                const float* __restrict__ node_sh,
                                                const int* __restrict__ start,
                                                const int* __restrict__ csr,
                                                const float* __restrict__ w1,
                                                const int* __restrict__ zarr,
                                                const float* __restrict__ w2,
                                                float* __restrict__ tab) {
    __shared__ float Gl[8 * 816];
    __shared__ float smid[8][368];
    __shared__ int szl[8];
    int t = threadIdx.x;
    int nbase = blockIdx.x * 8;
    for (int i = t; i < 8 * 816; i += 512) Gl[i] = 0.f;
    if (t < 8) szl[t] = zarr[nbase + t];
    __syncthreads();

    int e0 = start[nbase], e1 = start[nbase + 8];

    const float r3  = 0.57735026918962576f;
    const float r5  = 0.44721359549995794f;
    const float r6  = 0.40824829046386302f;
    const float r10 = 0.31622776601683794f;
    const float s30 = 0.18257418583505536f;
    const float rt3 = 1.7320508075688772f;
    const float c222 = 0.58554004376911990f;
    const float q6 = 0.40824829046386302f;
    const float h6 = 0.20412414523193151f;
    const float h2 = 0.35355339059327376f;
    const float r2c = 0.70710678118654752f;

    for (int idx = e0 + t; idx < e1; idx += 512) {
        int pk = csr[idx];
        int s = pk & 0xFFFF;
        int q = (pk >> 16) & 15;
        int r = (pk >> 20) & 7;
        float4 pd = pos4[nbase + r];
        float4 ps = pos4[s];
        float x = ps.x - pd.x;
        float y = ps.y - pd.y;
        float z = ps.z - pd.z;
        float B1[3], B2[5];
        sh_from_vec(x, y, z, B1, B2);
        const float4 nv0 = *(const float4*)(node_sh + s * 12);
        const float4 nv1 = *(const float4*)(node_sh + s * 12 + 4);
        float a0 = nv0.x;
        float A1[3] = {nv0.y, nv0.z, nv0.w};
        float A2[5] = {nv1.x, nv1.y, nv1.z, nv1.w, node_sh[s * 12 + 8]};
        float* gr = Gl + r * 816 + q * 51;

        atomicAdd(gr + 0, a0);
        atomicAdd(gr + 1, a0 * B1[0] * r3);
        atomicAdd(gr + 2, a0 * B1[1] * r3);
        atomicAdd(gr + 3, a0 * B1[2] * r3);
        atomicAdd(gr + 4, a0 * B2[0] * r5);
        atomicAdd(gr + 5, a0 * B2[1] * r5);
        atomicAdd(gr + 6, a0 * B2[2] * r5);
        atomicAdd(gr + 7, a0 * B2[3] * r5);
        atomicAdd(gr + 8, a0 * B2[4] * r5);
        atomicAdd(gr + 9,  A1[0] * r3);
        atomicAdd(gr + 10, A1[1] * r3);
        atomicAdd(gr + 11, A1[2] * r3);
        atomicAdd(gr + 12, -r3 * (A1[0] * B1[0] + A1[1] * B1[1] + A1[2] * B1[2]));
        atomicAdd(gr + 13, -r6 * (A1[1] * B1[2] - A1[2] * B1[1]));
        atomicAdd(gr + 14, -r6 * (A1[2] * B1[0] - A1[0] * B1[2]));
        atomicAdd(gr + 15, -r6 * (A1[0] * B1[1] - A1[1] * B1[0]));
        atomicAdd(gr + 16, r10 * (A1[0] * B1[2] + A1[2] * B1[0]));
        atomicAdd(gr + 17, r10 * (A1[0] * B1[1] + A1[1] * B1[0]));
        atomicAdd(gr + 18, s30 * (2.f * A1[1] * B1[1] - A1[0] * B1[0] - A1[2] * B1[2]));
        atomicAdd(gr + 19, r10 * (A1[1] * B1[2] + A1[2] * B1[1]));
        atomicAdd(gr + 20, r10 * (A1[2] * B1[2] - A1[0] * B1[0]));
        {
            float Byy = -B2[2] * q6 - B2[4] * r2c;
            float Bzz = 2.f * B2[2] * q6;
            float Bxx = -B2[2] * q6 + B2[4] * r2c;
            float Bxy = B2[0] * r2c;
            float Byz = B2[1] * r2c;
            float Bxz = B2[3] * r2c;
            atomicAdd(gr + 21, -r5 * (Byy * A1[0] + Byz * A1[1] + Bxy * A1[2]));
            atomicAdd(gr + 22, -r5 * (Byz * A1[0] + Bzz * A1[1] + Bxz * A1[2]));
            atomicAdd(gr + 23, -r5 * (Bxy * A1[0] + Bxz * A1[1] + Bxx * A1[2]));
        }
        atomicAdd(gr + 24, -s30 * (B2[1] * A1[0] - B2[3] * A1[2] + 2.f * B2[4] * A1[1]));
        atomicAdd(gr + 25, -s30 * (-B2[0] * A1[0] - rt3 * B2[2] * A1[2] + B2[3] * A1[1] - B2[4] * A1[2]));
        atomicAdd(gr + 26, -s30 * (rt3 * B2[1] * A1[2] - rt3 * B2[3] * A1[0]));
        atomicAdd(gr + 27, -s30 * (B2[0] * A1[2] - B2[1] * A1[1] + rt3 * B2[2] * A1[0] - B2[4] * A1[0]));
        atomicAdd(gr + 28, -s30 * (-2.f * B2[0] * A1[1] + B2[1] * A1[2] + B2[3] * A1[0]));
        atomicAdd(gr + 29, A2[0] * r5);
        atomicAdd(gr + 30, A2[1] * r5);
        atomicAdd(gr + 31, A2[2] * r5);
        atomicAdd(gr + 32, A2[3] * r5);
        atomicAdd(gr + 33, A2[4] * r5);
        {
            float Ayy = -A2[2] * q6 - A2[4] * r2c;
            float Azz = 2.f * A2[2] * q6;
            float Axx = -A2[2] * q6 + A2[4] * r2c;
            float Axy = A2[0] * r2c;
            float Ayz = A2[1] * r2c;
            float Axz = A2[3] * r2c;
            atomicAdd(gr + 34, -r5 * (Ayy * B1[0] + Ayz * B1[1] + Axy * B1[2]));
            atomicAdd(gr + 35, -r5 * (Ayz * B1[0] + Azz * B1[1] + Axz * B1[2]));
            atomicAdd(gr + 36, -r5 * (Axy * B1[0] + Axz * B1[1] + Axx * B1[2]));
        }
        atomicAdd(gr + 37, s30 * (A2[1] * B1[0] - A2[3] * B1[2] + 2.f * A2[4] * B1[1]));
        atomicAdd(gr + 38, s30 * (-A2[0] * B1[0] - rt3 * A2[2] * B1[2] + A2[3] * B1[1] - A2[4] * B1[2]));
        atomicAdd(gr + 39, s30 * (rt3 * A2[1] * B1[2] - rt3 * A2[3] * B1[0]));
        atomicAdd(gr + 40, s30 * (A2[0] * B1[2] - A2[1] * B1[1] + rt3 * A2[2] * B1[0] - A2[4] * B1[0]));
        atomicAdd(gr + 41, s30 * (-2.f * A2[0] * B1[1] + A2[1] * B1[2] + A2[3] * B1[0]));
        atomicAdd(gr + 42, r5 * (A2[0] * B2[0] + A2[1] * B2[1] + A2[2] * B2[2] +
                                 A2[3] * B2[3] + A2[4] * B2[4]));
        atomicAdd(gr + 43, s30 * (-A2[0] * B2[1] + A2[1] * B2[0] +
                                  rt3 * (A2[2] * B2[3] - A2[3] * B2[2]) +
                                  A2[3] * B2[4] - A2[4] * B2[3]));
        atomicAdd(gr + 44, s30 * (-2.f * A2[0] * B2[4] + 2.f * A2[4] * B2[0] -
                                  A2[1] * B2[3] + A2[3] * B2[1]));
        atomicAdd(gr + 45, s30 * (A2[0] * B2[3] - A2[3] * B2[0] +
                                  rt3 * (A2[1] * B2[2] - A2[2] * B2[1]) +
                                  A2[1] * B2[4] - A2[4] * B2[1]));
        atomicAdd(gr + 46, -c222 * (-q6 * (A2[0] * B2[2] + A2[2] * B2[0]) +
                                    h2 * (A2[1] * B2[3] + A2[3] * B2[1])));
        atomicAdd(gr + 47, -c222 * (h6 * (A2[1] * B2[2] + A2[2] * B2[1]) -
                                    h2 * (A2[1] * B2[4] + A2[4] * B2[1]) +
                                    h2 * (A2[0] * B2[3] + A2[3] * B2[0])));
        atomicAdd(gr + 48, -c222 * (q6 * (A2[2] * B2[2] - A2[0] * B2[0] - A2[4] * B2[4]) +
                                    h6 * (A2[1] * B2[1] + A2[3] * B2[3])));
        atomicAdd(gr + 49, -c222 * (h6 * (A2[3] * B2[2] + A2[2] * B2[3]) +
                                    h2 * (A2[3] * B2[4] + A2[4] * B2[3]) +
                                    h2 * (A2[0] * B2[1] + A2[1] * B2[0])));
        atomicAdd(gr + 50, -c222 * (-q6 * (A2[4] * B2[2] + A2[2] * B2[4]) +
                                    h2 * (A2[3] * B2[3] - A2[1] * B2[1])));
    }
    __syncthreads();

    // Phase 2: mid row -> smid (LDS), q-outer, acc[8].
    int j = t;
    if (j < 368) {
        float acc[8] = {0.f, 0.f, 0.f, 0.f, 0.f, 0.f, 0.f, 0.f};
        if (j < 64) {
            int w = j;
            for (int q = 0; q < 16; q++) {
                float wa = w1[q * 64 + w];
                float wb = w1[2048 + q * 64 + w];
                float wc = w1[5248 + q * 64 + w];
                const float* Gq = Gl + q * 51;
#pragma unroll
                for (int r2 = 0; r2 < 8; r2++) {
                    const float* gq = Gq + r2 * 816;
                    acc[r2] += gq[0] * wa + gq[12] * wb + gq[42] * wc;
                }
            }
#pragma unroll
            for (int r2 = 0; r2 < 8; r2++) smid[r2][j] = 0.33333333333333333f * acc[r2];
        } else if (j < 136) {
            int tt = j - 64, w = tt / 3, k = tt - 3 * w;
            for (int q = 0; q < 16; q++) {
                float wa = w1[3072 + q * 24 + w];
                float wb = w1[6272 + q * 24 + w];
                const float* Gq = Gl + q * 51;
#pragma unroll
                for (int r2 = 0; r2 < 8; r2++) {
                    const float* gq = Gq + r2 * 816;
                    acc[r2] += gq[13 + k] * wa + gq[43 + k] * wb;
                }
            }
#pragma unroll
            for (int r2 = 0; r2 < 8; r2++) smid[r2][j] = 0.70710678118654752f * acc[r2];
        } else if (j < 208) {
            int tt = j - 136, w = tt / 3, k = tt - 3 * w;
            for (int q = 0; q < 16; q++) {
                float wa = w1[1024 + q * 24 + w];
                float wb = w1[1664 + q * 24 + w];
                float wc = w1[3712 + q * 24 + w];
                float wd = w1[4608 + q * 24 + w];
                const float* Gq = Gl + q * 51;
#pragma unroll
                for (int r2 = 0; r2 < 8; r2++) {
                    const float* gq = Gq + r2 * 816;
                    acc[r2] += gq[1 + k] * wa + gq[9 + k] * wb +
                               gq[21 + k] * wc + gq[34 + k] * wd;
                }
            }
#pragma unroll
            for (int r2 = 0; r2 < 8; r2++) smid[r2][j] = 0.5f * acc[r2];
        } else if (j < 288) {
            int tt = j - 208, w = tt / 5, k = tt - 5 * w;
            for (int q = 0; q < 16; q++) {
                float wa = w1[1408 + q * 16 + w];
                float wb = w1[3456 + q * 16 + w];
                float wc = w1[4352 + q * 16 + w];
                float wd = w1[6656 + q * 16 + w];
                const float* Gq = Gl + q * 51;
#pragma unroll
                for (int r2 = 0; r2 < 8; r2++) {
                    const float* gq = Gq + r2 * 816;
                    acc[r2] += gq[4 + k] * wa + gq[16 + k] * wb +
                               gq[29 + k] * wc + gq[46 + k] * wd;
                }
            }
#pragma unroll
            for (int r2 = 0; r2 < 8; r2++) smid[r2][j] = 0.64549722436790280f * acc[r2];
        } else {
            int tt = j - 288, w = tt / 5, k = tt - 5 * w;
            for (int q = 0; q < 16; q++) {
                float wa = w1[4096 + q * 16 + w];
                float wb = w1[4992 + q * 16 + w];
                const float* Gq = Gl + q * 51;
#pragma unroll
                for (int r2 = 0; r2 < 8; r2++) {
                    const float* gq = Gq + r2 * 816;
                    acc[r2] += gq[24 + k] * wa + gq[37 + k] * wb;
                }
            }
#pragma unroll
            for (int r2 = 0; r2 < 8; r2++) smid[r2][j] = 0.91287092917527690f * acc[r2];
        }
    }
    __syncthreads();

    // Phase 3: tables. 8 nodes x 4 zd x 64 (j>=62 zero pad), 2048 entries.
    const float cT0f =  0.02830690f;
    const float cT1f = -0.02635231f;
    const float cT2f = -0.01634300f;
    const float cT3f =  0.01265893f;
    const float cT4f =  0.02041241f;
    for (int i = t; i < 2048; i += 512) {
        int rz = i >> 6;          // 0..31
        int jj = i & 63;          // 0..63
        int r  = rz >> 2;
        int zd = rz & 3;
        int q  = 4 * szl[r] + zd;
        const float* mr = &smid[r][0];
        float s = 0.f;
        if (jj < 6) {
            int w = jj;
            for (int u = 0; u < 64; u++)
                s += mr[u] * w2[(u * 16 + q) * 6 + w];
            s *= cT0f;
        } else if (jj < 9) {
            int c = jj - 6;
            for (int u = 0; u < 24; u++)
                s += mr[64 + 3 * u + c] * w2[6144 + u * 16 + q];
            s *= cT1f;
        } else if (jj < 27) {
            int c = (jj - 9) / 6, w = (jj - 9) % 6;
            for (int u = 0; u < 24; u++)
                s += mr[136 + 3 * u + c] * w2[6528 + (u * 16 + q) * 6 + w];
            s *= cT2f;
        } else if (jj < 57) {
            int c = (jj - 27) / 6, w = (jj - 27) % 6;
            for (int u = 0; u < 16; u++)
                s += mr[208 + 5 * u + c] * w2[8832 + (u * 16 + q) * 6 + w];
            s *= cT3f;
        } else if (jj < 62) {
            int c = jj - 57;
            for (int u = 0; u < 16; u++)
                s += mr[288 + 5 * u + c] * w2[10368 + u * 16 + q];
            s *= cT4f;
        }
        tab[((size_t)(nbase + r) * 4 + zd) * 64 + jj] = s;
    }
}

// ---------------- TP2 + graph reduce: dst-major over tables ----------------
// 512 thr = 8 waves = 8 dst nodes/block. Per edge: one coalesced tab-row
// load + mask-FMA factor. Per-node segmented reduce -> 7 atomics.
__global__ __launch_bounds__(512, 8) void k_out(const float4* __restrict__ pos4,
                                                const int* __restrict__ zarr,
                                                const int* __restrict__ batch,
                                                const int* __restrict__ start,
                                                const int* __restrict__ csr,
                                                const float* __restrict__ tab,
                                                float* __restrict__ out) {
    int wave = threadIdx.x >> 6;
    int lane = threadIdx.x & 63;
    int n = blockIdx.x * 8 + wave;       // dst node
    float4 pd = pos4[n];
    int zd = zarr[n];
    int s0 = start[n], s1 = start[n + 1];

    // per-lane static factor-select (fsel) and output-index (oidx)
    int fsel, oidx;
    if (lane < 6)       { fsel = 0;                  oidx = lane + 1; }
    else if (lane < 9)  { fsel = 1 + (lane - 6);     oidx = 0; }
    else if (lane < 27) { fsel = 1 + (lane - 9) / 6; oidx = (lane - 9) % 6 + 1; }
    else if (lane < 57) { fsel = 4 + (lane - 27) / 6; oidx = (lane - 27) % 6 + 1; }
    else if (lane < 62) { fsel = 4 + (lane - 57);    oidx = 0; }
    else                { fsel = -1;                 oidx = 7; }
    float f0 = (fsel == 0) ? 1.f : 0.f;
    float f1 = (fsel == 1) ? 1.f : 0.f;
    float f2 = (fsel == 2) ? 1.f : 0.f;
    float f3 = (fsel == 3) ? 1.f : 0.f;
    float f4 = (fsel == 4) ? 1.f : 0.f;
    float f5 = (fsel == 5) ? 1.f : 0.f;
    float f6 = (fsel == 6) ? 1.f : 0.f;
    float f7 = (fsel == 7) ? 1.f : 0.f;
    float f8 = (fsel == 8) ? 1.f : 0.f;

    float acc = 0.f;
    for (int idx = s0; idx < s1; ++idx) {
        int pk = csr[idx];
        pk = __builtin_amdgcn_readfirstlane(pk);
        int s = pk & 0xFFFF;
        float T = tab[((size_t)s * 4 + zd) * 64 + lane];   // coalesced 256B
        float4 ps = pos4[s];                               // uniform -> scalar
        float x = ps.x - pd.x;
        float y = ps.y - pd.y;
        float z = ps.z - pd.z;
        float B1[3], B2[5];
        sh_from_vec(x, y, z, B1, B2);
        float factor = f0 + f1 * B1[0] + f2 * B1[1] + f3 * B1[2]
                     + f4 * B2[0] + f5 * B2[1] + f6 * B2[2]
                     + f7 * B2[3] + f8 * B2[4];
        acc += T * factor;
    }

    // segmented 7-way wave reduce (once per node)
    float ov[7];
#pragma unroll
    for (int w = 0; w < 7; w++) ov[w] = (oidx == w) ? acc : 0.f;
#pragma unroll
    for (int off = 32; off > 0; off >>= 1)
#pragma unroll
        for (int w = 0; w < 7; w++) ov[w] += __shfl_down(ov[w], off, 64);
    if (lane == 0) {
        float* og = out + batch[n] * 7;
#pragma unroll
        for (int w = 0; w < 7; w++) atomicAdd(og + w, ov[w]);
    }
}

// ---------------------------------------------------------------------------
extern "C" void kernel_launch(void* const* d_in, const int* in_sizes, int n_in,
                              void* d_out, int out_size, void* d_ws, size_t ws_size,
                              hipStream_t stream) {
    const float* pos  = (const float*)d_in[0];
    const int*   z    = (const int*)d_in[1];
    const int*   bat  = (const int*)d_in[2];
    const int*   esrc = (const int*)d_in[3];
    const int*   edst = (const int*)d_in[4];
    const float* w1   = (const float*)d_in[5];
    const float* w2   = (const float*)d_in[6];
    float* out = (float*)d_out;

    int*   wsI = (int*)d_ws;
    float* wsF = (float*)d_ws;
    int* counts  = wsI + 0;
    int* start   = wsI + 32768;
    int* cursor  = wsI + 65536;
    int* csr     = wsI + 98304;
    float4* pos4   = (float4*)(wsF + 425984);
    float* node_sh = wsF + 524288;
    float* tab     = wsF + 1048576;

    k_zero<<<64, 256, 0, stream>>>(pos, counts, out, pos4);
    k_hist<<<(N_EDGES + 255) / 256, 256, 0, stream>>>(edst, counts);
    k_scan<<<1, 1024, 0, stream>>>(counts, start, cursor);
    k_fill<<<(N_EDGES + 255) / 256, 256, 0, stream>>>(esrc, edst, z, cursor, csr);
    k_nodesh<<<NN_NODES / 16, 256, 0, stream>>>(pos4, start, csr, node_sh);
    k_mid<<<NN_NODES / 8, 512, 0, stream>>>(pos4, node_sh, start, csr, w1, z, w2, tab);
    k_out<<<NN_NODES / 8, 512, 0, stream>>>(pos4, z, bat, start, csr, tab, out);
}

// Round 8
// 392.123 us; speedup vs baseline: 1.4748x; 1.3462x over previous
//
#include <hip/hip_runtime.h>

// ---------------------------------------------------------------------------
// InvariantPolynomial, round 10: coalesced phase-3 via transposed w2p.
//
// Round-9 post-mortem: k_out fixed (atomics 2.24M->140K, gone from top-5),
// but fused phase 3 in k_mid cost ~180us: per-thread serial u-loops of
// SCATTERED 4B w2 reads (stride 384B) + 5-way branch divergence.
//
// Fix: k_wprep pre-transposes w2 -> w2p[q][u][jj] (256KB, L2-resident,
// cT* factors absorbed, zero-padded). Phase 3 becomes wave-per-node:
// lane=jj, uniform u-loop, ONE coalesced 256B load per iteration
// (w2p[q][u][lane]) + LDS broadcast smid read. m-index via per-lane
// mbase/mstride with clamp (pad weights are 0 so clamped m is harmless).
//
// ws layout (ints/floats):
//   counts  @ int   [0      , 20000)
//   start   @ int   [32768  , 52769)
//   cursor  @ int   [65536  , 85536)
//   csr     @ int   [98304  , 418304)   dst-CSR: s | q<<16 | (d&15)<<20
//   pos4    @ float [425984 , 505984)   20000 x 4
//   node_sh @ float [524288 , 764288)   20000 x 12 (9 used, inv_nn folded)
//   w2p     @ float [786432 , 851968)   16 x 64 x 64
//   tab     @ float [1048576, 6168576)  20000 x 4 x 64
// ---------------------------------------------------------------------------

#define N_EDGES   320000
#define NN_NODES  20000
#define NN_GRAPHS 5000

__device__ __forceinline__ void sh_from_vec(float x, float y, float z,
                                            float* B1, float* B2) {
    const float s3   = 1.7320508075688772f;
    const float s15  = 3.8729833462074170f;
    const float s5h  = 1.1180339887498949f;
    const float s15h = 1.9364916731037085f;
    B1[0] = s3 * y; B1[1] = s3 * z; B1[2] = s3 * x;
    float r2 = x * x + y * y + z * z;
    B2[0] = s15 * x * y;
    B2[1] = s15 * y * z;
    B2[2] = s5h * (3.f * z * z - r2);
    B2[3] = s15 * x * z;
    B2[4] = s15h * (x * x - y * y);
}

// --------------------------- zero + pos4 pack ------------------------------
__global__ __launch_bounds__(256) void k_zero(const float* __restrict__ pos,
                                              int* __restrict__ counts,
                                              float* __restrict__ out,
                                              float4* __restrict__ pos4) {
    int tid = blockIdx.x * blockDim.x + threadIdx.x;
    int stride = gridDim.x * blockDim.x;
    for (int i = tid; i < NN_NODES; i += stride) counts[i] = 0;
    for (int i = tid; i < NN_GRAPHS * 7; i += stride) out[i] = 0.f;
    for (int i = tid; i < NN_NODES; i += stride) {
        float4 p;
        p.x = pos[3 * i]; p.y = pos[3 * i + 1]; p.z = pos[3 * i + 2]; p.w = 0.f;
        pos4[i] = p;
    }
}

// --------------------------- histogram -------------------------------------
__global__ __launch_bounds__(256) void k_hist(const int* __restrict__ edst,
                                              int* __restrict__ counts) {
    int e = blockIdx.x * blockDim.x + threadIdx.x;
    if (e < N_EDGES) atomicAdd(&counts[edst[e]], 1);
}

// --------------------------- exclusive scan (1 block of 1024) --------------
__global__ __launch_bounds__(1024) void k_scan(const int* __restrict__ counts,
                                               int* __restrict__ start,
                                               int* __restrict__ cursor) {
    __shared__ int sdata[1024];
    __shared__ int carry;
    int tid = threadIdx.x;
    if (tid == 0) carry = 0;
    __syncthreads();
    for (int base = 0; base < NN_NODES; base += 1024) {
        int i = base + tid;
        int v = (i < NN_NODES) ? counts[i] : 0;
        sdata[tid] = v;
        __syncthreads();
        for (int off = 1; off < 1024; off <<= 1) {
            int t = (tid >= off) ? sdata[tid - off] : 0;
            __syncthreads();
            sdata[tid] += t;
            __syncthreads();
        }
        int incl = sdata[tid];
        int c = carry;
        if (i < NN_NODES) {
            int excl = c + incl - v;
            start[i] = excl;
            cursor[i] = excl;
        }
        __syncthreads();
        if (tid == 0) carry = c + sdata[1023];
        __syncthreads();
    }
    if (tid == 0) start[NN_NODES] = carry;   // = N_EDGES
}

// --------------------------- dst-CSR fill ----------------------------------
__global__ __launch_bounds__(256) void k_fill(const int* __restrict__ esrc,
                                              const int* __restrict__ edst,
                                              const int* __restrict__ zarr,
                                              int* __restrict__ cursor,
                                              int* __restrict__ csr) {
    int e = blockIdx.x * blockDim.x + threadIdx.x;
    if (e >= N_EDGES) return;
    int d = edst[e];
    int s = esrc[e];
    int q = 4 * zarr[s] + zarr[d];
    int p = atomicAdd(&cursor[d], 1);
    csr[p] = s | (q << 16) | ((d & 15) << 20);
}

// ----------------- w2 -> w2p[q][u][jj] transpose (cT absorbed) -------------
__global__ __launch_bounds__(256) void k_wprep(const float* __restrict__ w2,
                                               float* __restrict__ w2p) {
    const float cT0f =  0.02830690f;
    const float cT1f = -0.02635231f;
    const float cT2f = -0.01634300f;
    const float cT3f =  0.01265893f;
    const float cT4f =  0.02041241f;
    int idx = blockIdx.x * 256 + threadIdx.x;    // (q*64+u)*64+jj
    if (idx >= 16 * 64 * 64) return;
    int jj = idx & 63;
    int u  = (idx >> 6) & 63;
    int q  = idx >> 12;
    float v = 0.f;
    if (jj < 6) {
        v = cT0f * w2[(u * 16 + q) * 6 + jj];
    } else if (jj < 9) {
        if (u < 24) v = cT1f * w2[6144 + u * 16 + q];
    } else if (jj < 27) {
        int w = (jj - 9) % 6;
        if (u < 24) v = cT2f * w2[6528 + (u * 16 + q) * 6 + w];
    } else if (jj < 57) {
        int w = (jj - 27) % 6;
        if (u < 16) v = cT3f * w2[8832 + (u * 16 + q) * 6 + w];
    } else if (jj < 62) {
        if (u < 16) v = cT4f * w2[10368 + u * 16 + q];
    }
    w2p[idx] = v;
}

// ------------------- node_sh: edge-parallel, 16 nodes/block ----------------
__global__ __launch_bounds__(256) void k_nodesh(const float4* __restrict__ pos4,
                                                const int* __restrict__ start,
                                                const int* __restrict__ csr,
                                                float* __restrict__ node_sh) {
    __shared__ float ns[16][12];
    int t = threadIdx.x;
    if (t < 192) ns[t / 12][t % 12] = 0.f;
    __syncthreads();
    int nbase = blockIdx.x * 16;
    int e0 = start[nbase], e1 = start[nbase + 16];
    for (int idx = e0 + t; idx < e1; idx += 256) {
        int pk = csr[idx];
        int s = pk & 0xFFFF;
        int r = (pk >> 20) & 15;
        float4 pd = pos4[nbase + r];
        float4 ps = pos4[s];
        float x = ps.x - pd.x;
        float y = ps.y - pd.y;
        float z = ps.z - pd.z;
        float B1[3], B2[5];
        sh_from_vec(x, y, z, B1, B2);
        float* nr = &ns[r][0];
        atomicAdd(nr + 0, 1.f);
        atomicAdd(nr + 1, B1[0]); atomicAdd(nr + 2, B1[1]); atomicAdd(nr + 3, B1[2]);
        atomicAdd(nr + 4, B2[0]); atomicAdd(nr + 5, B2[1]); atomicAdd(nr + 6, B2[2]);
        atomicAdd(nr + 7, B2[3]); atomicAdd(nr + 8, B2[4]);
    }
    __syncthreads();
    if (t < 144) {
        int r = t / 9, c = t % 9;
        const float inv_nn = 0.57735026918962576f;
        node_sh[(size_t)(nbase + r) * 12 + c] = ns[r][c] * inv_nn;
    }
}

// ------- fused TP1 -> mid (LDS) -> TP2 tables (coalesced w2p) --------------
__global__ __launch_bounds__(512, 6) void k_mid(const float4* __restrict__ pos4,
                                                const float* __restrict__ node_sh,
                                                const int* __restrict__ start,
                                                const int* __restrict__ csr,
                                                const float* __restrict__ w1,
                                                const int* __restrict__ zarr,
                                                const float* __restrict__ w2p,
                                                float* __restrict__ tab) {
    __shared__ float Gl[8 * 816];
    __shared__ float smid[8][368];
    __shared__ int szl[8];
    int t = threadIdx.x;
    int nbase = blockIdx.x * 8;
    for (int i = t; i < 8 * 816; i += 512) Gl[i] = 0.f;
    if (t < 8) szl[t] = zarr[nbase + t];
    __syncthreads();

    int e0 = start[nbase], e1 = start[nbase + 8];

    const float r3  = 0.57735026918962576f;
    const float r5  = 0.44721359549995794f;
    const float r6  = 0.40824829046386302f;
    const float r10 = 0.31622776601683794f;
    const float s30 = 0.18257418583505536f;
    const float rt3 = 1.7320508075688772f;
    const float c222 = 0.58554004376911990f;
    const float q6 = 0.40824829046386302f;
    const float h6 = 0.20412414523193151f;
    const float h2 = 0.35355339059327376f;
    const float r2c = 0.70710678118654752f;

    for (int idx = e0 + t; idx < e1; idx += 512) {
        int pk = csr[idx];
        int s = pk & 0xFFFF;
        int q = (pk >> 16) & 15;
        int r = (pk >> 20) & 7;
        float4 pd = pos4[nbase + r];
        float4 ps = pos4[s];
        float x = ps.x - pd.x;
        float y = ps.y - pd.y;
        float z = ps.z - pd.z;
        float B1[3], B2[5];
        sh_from_vec(x, y, z, B1, B2);
        const float4 nv0 = *(const float4*)(node_sh + s * 12);
        const float4 nv1 = *(const float4*)(node_sh + s * 12 + 4);
        float a0 = nv0.x;
        float A1[3] = {nv0.y, nv0.z, nv0.w};
        float A2[5] = {nv1.x, nv1.y, nv1.z, nv1.w, node_sh[s * 12 + 8]};
        float* gr = Gl + r * 816 + q * 51;

        atomicAdd(gr + 0, a0);
        atomicAdd(gr + 1, a0 * B1[0] * r3);
        atomicAdd(gr + 2, a0 * B1[1] * r3);
        atomicAdd(gr + 3, a0 * B1[2] * r3);
        atomicAdd(gr + 4, a0 * B2[0] * r5);
        atomicAdd(gr + 5, a0 * B2[1] * r5);
        atomicAdd(gr + 6, a0 * B2[2] * r5);
        atomicAdd(gr + 7, a0 * B2[3] * r5);
        atomicAdd(gr + 8, a0 * B2[4] * r5);
        atomicAdd(gr + 9,  A1[0] * r3);
        atomicAdd(gr + 10, A1[1] * r3);
        atomicAdd(gr + 11, A1[2] * r3);
        atomicAdd(gr + 12, -r3 * (A1[0] * B1[0] + A1[1] * B1[1] + A1[2] * B1[2]));
        atomicAdd(gr + 13, -r6 * (A1[1] * B1[2] - A1[2] * B1[1]));
        atomicAdd(gr + 14, -r6 * (A1[2] * B1[0] - A1[0] * B1[2]));
        atomicAdd(gr + 15, -r6 * (A1[0] * B1[1] - A1[1] * B1[0]));
        atomicAdd(gr + 16, r10 * (A1[0] * B1[2] + A1[2] * B1[0]));
        atomicAdd(gr + 17, r10 * (A1[0] * B1[1] + A1[1] * B1[0]));
        atomicAdd(gr + 18, s30 * (2.f * A1[1] * B1[1] - A1[0] * B1[0] - A1[2] * B1[2]));
        atomicAdd(gr + 19, r10 * (A1[1] * B1[2] + A1[2] * B1[1]));
        atomicAdd(gr + 20, r10 * (A1[2] * B1[2] - A1[0] * B1[0]));
        {
            float Byy = -B2[2] * q6 - B2[4] * r2c;
            float Bzz = 2.f * B2[2] * q6;
            float Bxx = -B2[2] * q6 + B2[4] * r2c;
            float Bxy = B2[0] * r2c;
            float Byz = B2[1] * r2c;
            float Bxz = B2[3] * r2c;
            atomicAdd(gr + 21, -r5 * (Byy * A1[0] + Byz * A1[1] + Bxy * A1[2]));
            atomicAdd(gr + 22, -r5 * (Byz * A1[0] + Bzz * A1[1] + Bxz * A1[2]));
            atomicAdd(gr + 23, -r5 * (Bxy * A1[0] + Bxz * A1[1] + Bxx * A1[2]));
        }
        atomicAdd(gr + 24, -s30 * (B2[1] * A1[0] - B2[3] * A1[2] + 2.f * B2[4] * A1[1]));
        atomicAdd(gr + 25, -s30 * (-B2[0] * A1[0] - rt3 * B2[2] * A1[2] + B2[3] * A1[1] - B2[4] * A1[2]));
        atomicAdd(gr + 26, -s30 * (rt3 * B2[1] * A1[2] - rt3 * B2[3] * A1[0]));
        atomicAdd(gr + 27, -s30 * (B2[0] * A1[2] - B2[1] * A1[1] + rt3 * B2[2] * A1[0] - B2[4] * A1[0]));
        atomicAdd(gr + 28, -s30 * (-2.f * B2[0] * A1[1] + B2[1] * A1[2] + B2[3] * A1[0]));
        atomicAdd(gr + 29, A2[0] * r5);
        atomicAdd(gr + 30, A2[1] * r5);
        atomicAdd(gr + 31, A2[2] * r5);
        atomicAdd(gr + 32, A2[3] * r5);
        atomicAdd(gr + 33, A2[4] * r5);
        {
            float Ayy = -A2[2] * q6 - A2[4] * r2c;
            float Azz = 2.f * A2[2] * q6;
            float Axx = -A2[2] * q6 + A2[4] * r2c;
            float Axy = A2[0] * r2c;
            float Ayz = A2[1] * r2c;
            float Axz = A2[3] * r2c;
            atomicAdd(gr + 34, -r5 * (Ayy * B1[0] + Ayz * B1[1] + Axy * B1[2]));
            atomicAdd(gr + 35, -r5 * (Ayz * B1[0] + Azz * B1[1] + Axz * B1[2]));
            atomicAdd(gr + 36, -r5 * (Axy * B1[0] + Axz * B1[1] + Axx * B1[2]));
        }
        atomicAdd(gr + 37, s30 * (A2[1] * B1[0] - A2[3] * B1[2] + 2.f * A2[4] * B1[1]));
        atomicAdd(gr + 38, s30 * (-A2[0] * B1[0] - rt3 * A2[2] * B1[2] + A2[3] * B1[1] - A2[4] * B1[2]));
        atomicAdd(gr + 39, s30 * (rt3 * A2[1] * B1[2] - rt3 * A2[3] * B1[0]));
        atomicAdd(gr + 40, s30 * (A2[0] * B1[2] - A2[1] * B1[1] + rt3 * A2[2] * B1[0] - A2[4] * B1[0]));
        atomicAdd(gr + 41, s30 * (-2.f * A2[0] * B1[1] + A2[1] * B1[2] + A2[3] * B1[0]));
        atomicAdd(gr + 42, r5 * (A2[0] * B2[0] + A2[1] * B2[1] + A2[2] * B2[2] +
                                 A2[3] * B2[3] + A2[4] * B2[4]));
        atomicAdd(gr + 43, s30 * (-A2[0] * B2[1] + A2[1] * B2[0] +
                                  rt3 * (A2[2] * B2[3] - A2[3] * B2[2]) +
                                  A2[3] * B2[4] - A2[4] * B2[3]));
        atomicAdd(gr + 44, s30 * (-2.f * A2[0] * B2[4] + 2.f * A2[4] * B2[0] -
                                  A2[1] * B2[3] + A2[3] * B2[1]));
        atomicAdd(gr + 45, s30 * (A2[0] * B2[3] - A2[3] * B2[0] +
                                  rt3 * (A2[1] * B2[2] - A2[2] * B2[1]) +
                                  A2[1] * B2[4] - A2[4] * B2[1]));
        atomicAdd(gr + 46, -c222 * (-q6 * (A2[0] * B2[2] + A2[2] * B2[0]) +
                                    h2 * (A2[1] * B2[3] + A2[3] * B2[1])));
        atomicAdd(gr + 47, -c222 * (h6 * (A2[1] * B2[2] + A2[2] * B2[1]) -
                                    h2 * (A2[1] * B2[4] + A2[4] * B2[1]) +
                                    h2 * (A2[0] * B2[3] + A2[3] * B2[0])));
        atomicAdd(gr + 48, -c222 * (q6 * (A2[2] * B2[2] - A2[0] * B2[0] - A2[4] * B2[4]) +
                                    h6 * (A2[1] * B2[1] + A2[3] * B2[3])));
        atomicAdd(gr + 49, -c222 * (h6 * (A2[3] * B2[2] + A2[2] * B2[3]) +
                                    h2 * (A2[3] * B2[4] + A2[4] * B2[3]) +
                                    h2 * (A2[0] * B2[1] + A2[1] * B2[0])));
        atomicAdd(gr + 50, -c222 * (-q6 * (A2[4] * B2[2] + A2[2] * B2[4]) +
                                    h2 * (A2[3] * B2[3] - A2[1] * B2[1])));
    }
    __syncthreads();

    // Phase 2: mid row -> smid (LDS), q-outer, acc[8].
    int j = t;
    if (j < 368) {
        float acc[8] = {0.f, 0.f, 0.f, 0.f, 0.f, 0.f, 0.f, 0.f};
        if (j < 64) {
            int w = j;
            for (int q = 0; q < 16; q++) {
                float wa = w1[q * 64 + w];
                float wb = w1[2048 + q * 64 + w];
                float wc = w1[5248 + q * 64 + w];
                const float* Gq = Gl + q * 51;
#pragma unroll
                for (int r2 = 0; r2 < 8; r2++) {
                    const float* gq = Gq + r2 * 816;
                    acc[r2] += gq[0] * wa + gq[12] * wb + gq[42] * wc;
                }
            }
#pragma unroll
            for (int r2 = 0; r2 < 8; r2++) smid[r2][j] = 0.33333333333333333f * acc[r2];
        } else if (j < 136) {
            int tt = j - 64, w = tt / 3, k = tt - 3 * w;
            for (int q = 0; q < 16; q++) {
                float wa = w1[3072 + q * 24 + w];
                float wb = w1[6272 + q * 24 + w];
                const float* Gq = Gl + q * 51;
#pragma unroll
                for (int r2 = 0; r2 < 8; r2++) {
                    const float* gq = Gq + r2 * 816;
                    acc[r2] += gq[13 + k] * wa + gq[43 + k] * wb;
                }
            }
#pragma unroll
            for (int r2 = 0; r2 < 8; r2++) smid[r2][j] = 0.70710678118654752f * acc[r2];
        } else if (j < 208) {
            int tt = j - 136, w = tt / 3, k = tt - 3 * w;
            for (int q = 0; q < 16; q++) {
                float wa = w1[1024 + q * 24 + w];
                float wb = w1[1664 + q * 24 + w];
                float wc = w1[3712 + q * 24 + w];
                float wd = w1[4608 + q * 24 + w];
                const float* Gq = Gl + q * 51;
#pragma unroll
                for (int r2 = 0; r2 < 8; r2++) {
                    const float* gq = Gq + r2 * 816;
                    acc[r2] += gq[1 + k] * wa + gq[9 + k] * wb +
                               gq[21 + k] * wc + gq[34 + k] * wd;
                }
            }
#pragma unroll
            for (int r2 = 0; r2 < 8; r2++) smid[r2][j] = 0.5f * acc[r2];
        } else if (j < 288) {
            int tt = j - 208, w = tt / 5, k = tt - 5 * w;
            for (int q = 0; q < 16; q++) {
                float wa = w1[1408 + q * 16 + w];
                float wb = w1[3456 + q * 16 + w];
                float wc = w1[4352 + q * 16 + w];
                float wd = w1[6656 + q * 16 + w];
                const float* Gq = Gl + q * 51;
#pragma unroll
                for (int r2 = 0; r2 < 8; r2++) {
                    const float* gq = Gq + r2 * 816;
                    acc[r2] += gq[4 + k] * wa + gq[16 + k] * wb +
                               gq[29 + k] * wc + gq[46 + k] * wd;
                }
            }
#pragma unroll
            for (int r2 = 0; r2 < 8; r2++) smid[r2][j] = 0.64549722436790280f * acc[r2];
        } else {
            int tt = j - 288, w = tt / 5, k = tt - 5 * w;
            for (int q = 0; q < 16; q++) {
                float wa = w1[4096 + q * 16 + w];
                float wb = w1[4992 + q * 16 + w];
                const float* Gq = Gl + q * 51;
#pragma unroll
                for (int r2 = 0; r2 < 8; r2++) {
                    const float* gq = Gq + r2 * 816;
                    acc[r2] += gq[24 + k] * wa + gq[37 + k] * wb;
                }
            }
#pragma unroll
            for (int r2 = 0; r2 < 8; r2++) smid[r2][j] = 0.91287092917527690f * acc[r2];
        }
    }
    __syncthreads();

    // Phase 3: wave-per-node, lane = jj; coalesced w2p[q][u][lane] loads.
    {
        int wave = t >> 6;
        int lane = t & 63;
        int r = wave;
        int mbase, mstride, ulim;
        if (lane < 6)       { mbase = 0;                mstride = 1; ulim = 64; }
        else if (lane < 9)  { mbase = 64 + (lane - 6);  mstride = 3; ulim = 24; }
        else if (lane < 27) { mbase = 136 + (lane - 9) / 6;  mstride = 3; ulim = 24; }
        else if (lane < 57) { mbase = 208 + (lane - 27) / 6; mstride = 5; ulim = 16; }
        else if (lane < 62) { mbase = 288 + (lane - 57);     mstride = 5; ulim = 16; }
        else                { mbase = 0;                mstride = 0; ulim = 1; }
        int ulim1 = ulim - 1;
        const float* mr = &smid[r][0];
        int zs = szl[r];
        for (int zd = 0; zd < 4; zd++) {
            int q = 4 * zs + zd;
            const float* wp = w2p + (size_t)q * 4096 + lane;
            float s0 = 0.f, s1 = 0.f;
#pragma unroll 8
            for (int u = 0; u < 64; u += 2) {
                int um0 = (u < ulim) ? u : ulim1;
                int um1 = (u + 1 < ulim) ? u + 1 : ulim1;
                s0 += mr[mbase + mstride * um0] * wp[u * 64];
                s1 += mr[mbase + mstride * um1] * wp[(u + 1) * 64];
            }
            tab[((size_t)(nbase + r) * 4 + zd) * 64 + lane] = s0 + s1;
        }
    }
}

// ---------------- TP2 + graph reduce: dst-major over tables ----------------
__global__ __launch_bounds__(512, 8) void k_out(const float4* __restrict__ pos4,
                                                const int* __restrict__ zarr,
                                                const int* __restrict__ batch,
                                                const int* __restrict__ start,
                                                const int* __restrict__ csr,
                                                const float* __restrict__ tab,
                                                float* __restrict__ out) {
    int wave = threadIdx.x >> 6;
    int lane = threadIdx.x & 63;
    int n = blockIdx.x * 8 + wave;       // dst node
    float4 pd = pos4[n];
    int zd = zarr[n];
    int s0 = start[n], s1 = start[n + 1];

    int fsel, oidx;
    if (lane < 6)       { fsel = 0;                  oidx = lane + 1; }
    else if (lane < 9)  { fsel = 1 + (lane - 6);     oidx = 0; }
    else if (lane < 27) { fsel = 1 + (lane - 9) / 6; oidx = (lane - 9) % 6 + 1; }
    else if (lane < 57) { fsel = 4 + (lane - 27) / 6; oidx = (lane - 27) % 6 + 1; }
    else if (lane < 62) { fsel = 4 + (lane - 57);    oidx = 0; }
    else                { fsel = -1;                 oidx = 7; }
    float f0 = (fsel == 0) ? 1.f : 0.f;
    float f1 = (fsel == 1) ? 1.f : 0.f;
    float f2 = (fsel == 2) ? 1.f : 0.f;
    float f3 = (fsel == 3) ? 1.f : 0.f;
    float f4 = (fsel == 4) ? 1.f : 0.f;
    float f5 = (fsel == 5) ? 1.f : 0.f;
    float f6 = (fsel == 6) ? 1.f : 0.f;
    float f7 = (fsel == 7) ? 1.f : 0.f;
    float f8 = (fsel == 8) ? 1.f : 0.f;

    float acc = 0.f;
    for (int idx = s0; idx < s1; ++idx) {
        int pk = csr[idx];
        pk = __builtin_amdgcn_readfirstlane(pk);
        int s = pk & 0xFFFF;
        float T = tab[((size_t)s * 4 + zd) * 64 + lane];   // coalesced 256B
        float4 ps = pos4[s];                               // uniform -> scalar
        float x = ps.x - pd.x;
        float y = ps.y - pd.y;
        float z = ps.z - pd.z;
        float B1[3], B2[5];
        sh_from_vec(x, y, z, B1, B2);
        float factor = f0 + f1 * B1[0] + f2 * B1[1] + f3 * B1[2]
                     + f4 * B2[0] + f5 * B2[1] + f6 * B2[2]
                     + f7 * B2[3] + f8 * B2[4];
        acc += T * factor;
    }

    float ov[7];
#pragma unroll
    for (int w = 0; w < 7; w++) ov[w] = (oidx == w) ? acc : 0.f;
#pragma unroll
    for (int off = 32; off > 0; off >>= 1)
#pragma unroll
        for (int w = 0; w < 7; w++) ov[w] += __shfl_down(ov[w], off, 64);
    if (lane == 0) {
        float* og = out + batch[n] * 7;
#pragma unroll
        for (int w = 0; w < 7; w++) atomicAdd(og + w, ov[w]);
    }
}

// ---------------------------------------------------------------------------
extern "C" void kernel_launch(void* const* d_in, const int* in_sizes, int n_in,
                              void* d_out, int out_size, void* d_ws, size_t ws_size,
                              hipStream_t stream) {
    const float* pos  = (const float*)d_in[0];
    const int*   z    = (const int*)d_in[1];
    const int*   bat  = (const int*)d_in[2];
    const int*   esrc = (const int*)d_in[3];
    const int*   edst = (const int*)d_in[4];
    const float* w1   = (const float*)d_in[5];
    const float* w2   = (const float*)d_in[6];
    float* out = (float*)d_out;

    int*   wsI = (int*)d_ws;
    float* wsF = (float*)d_ws;
    int* counts  = wsI + 0;
    int* start   = wsI + 32768;
    int* cursor  = wsI + 65536;
    int* csr     = wsI + 98304;
    float4* pos4   = (float4*)(wsF + 425984);
    float* node_sh = wsF + 524288;
    float* w2p     = wsF + 786432;
    float* tab     = wsF + 1048576;

    k_zero<<<64, 256, 0, stream>>>(pos, counts, out, pos4);
    k_hist<<<(N_EDGES + 255) / 256, 256, 0, stream>>>(edst, counts);
    k_scan<<<1, 1024, 0, stream>>>(counts, start, cursor);
    k_fill<<<(N_EDGES + 255) / 256, 256, 0, stream>>>(esrc, edst, z, cursor, csr);
    k_wprep<<<256, 256, 0, stream>>>(w2, w2p);
    k_nodesh<<<NN_NODES / 16, 256, 0, stream>>>(pos4, start, csr, node_sh);
    k_mid<<<NN_NODES / 8, 512, 0, stream>>>(pos4, node_sh, start, csr, w1, z, w2p, tab);
    k_out<<<NN_NODES / 8, 512, 0, stream>>>(pos4, z, bat, start, csr, tab, out);
}

// Round 9
// 377.758 us; speedup vs baseline: 1.5309x; 1.0380x over previous
//
#include <hip/hip_runtime.h>

// ---------------------------------------------------------------------------
// InvariantPolynomial, round 11: exploit z_dst-fixed -> 4x cut in phase 2.
//
// Round-10 audit: k_mid 197us; LDS port is the wall -- phase 2 issued ~2700
// broadcast ds_reads/block over ALL 16 q, but per node only q = 4*zs + z_r
// (4 cells) are nonzero (z_dst fixed per node). Phase 1 writes only those.
//
// This round:
//  * Gl shrunk [8][16][51] -> [8][4][51] (6.5KB; phase-1 index zs = q>>2).
//  * Phase 2: q-loop keeps shared w1 loads; per (q,r2) the G-read+FMA happens
//    only when z_r2 == (q&3) -- scalar branch via readfirstlane'd szl.
//    ds_reads/FMAs drop 4x.
//  * LDS 38.4 -> 18.4KB -> 4 blocks/CU (2048 thr) = 100% occupancy.
//  * Phase 3 (w2p tables) unchanged.
//
// ws layout (ints/floats):
//   counts  @ int   [0      , 20000)
//   start   @ int   [32768  , 52769)
//   cursor  @ int   [65536  , 85536)
//   csr     @ int   [98304  , 418304)   dst-CSR: s | q<<16 | (d&15)<<20
//   pos4    @ float [425984 , 505984)   20000 x 4
//   node_sh @ float [524288 , 764288)   20000 x 12 (9 used, inv_nn folded)
//   w2p     @ float [786432 , 851968)   16 x 64 x 64
//   tab     @ float [1048576, 6168576)  20000 x 4 x 64
// ---------------------------------------------------------------------------

#define N_EDGES   320000
#define NN_NODES  20000
#define NN_GRAPHS 5000

__device__ __forceinline__ void sh_from_vec(float x, float y, float z,
                                            float* B1, float* B2) {
    const float s3   = 1.7320508075688772f;
    const float s15  = 3.8729833462074170f;
    const float s5h  = 1.1180339887498949f;
    const float s15h = 1.9364916731037085f;
    B1[0] = s3 * y; B1[1] = s3 * z; B1[2] = s3 * x;
    float r2 = x * x + y * y + z * z;
    B2[0] = s15 * x * y;
    B2[1] = s15 * y * z;
    B2[2] = s5h * (3.f * z * z - r2);
    B2[3] = s15 * x * z;
    B2[4] = s15h * (x * x - y * y);
}

// --------------------------- zero + pos4 pack ------------------------------
__global__ __launch_bounds__(256) void k_zero(const float* __restrict__ pos,
                                              int* __restrict__ counts,
                                              float* __restrict__ out,
                                              float4* __restrict__ pos4) {
    int tid = blockIdx.x * blockDim.x + threadIdx.x;
    int stride = gridDim.x * blockDim.x;
    for (int i = tid; i < NN_NODES; i += stride) counts[i] = 0;
    for (int i = tid; i < NN_GRAPHS * 7; i += stride) out[i] = 0.f;
    for (int i = tid; i < NN_NODES; i += stride) {
        float4 p;
        p.x = pos[3 * i]; p.y = pos[3 * i + 1]; p.z = pos[3 * i + 2]; p.w = 0.f;
        pos4[i] = p;
    }
}

// --------------------------- histogram -------------------------------------
__global__ __launch_bounds__(256) void k_hist(const int* __restrict__ edst,
                                              int* __restrict__ counts) {
    int e = blockIdx.x * blockDim.x + threadIdx.x;
    if (e < N_EDGES) atomicAdd(&counts[edst[e]], 1);
}

// --------------------------- exclusive scan (1 block of 1024) --------------
__global__ __launch_bounds__(1024) void k_scan(const int* __restrict__ counts,
                                               int* __restrict__ start,
                                               int* __restrict__ cursor) {
    __shared__ int sdata[1024];
    __shared__ int carry;
    int tid = threadIdx.x;
    if (tid == 0) carry = 0;
    __syncthreads();
    for (int base = 0; base < NN_NODES; base += 1024) {
        int i = base + tid;
        int v = (i < NN_NODES) ? counts[i] : 0;
        sdata[tid] = v;
        __syncthreads();
        for (int off = 1; off < 1024; off <<= 1) {
            int t = (tid >= off) ? sdata[tid - off] : 0;
            __syncthreads();
            sdata[tid] += t;
            __syncthreads();
        }
        int incl = sdata[tid];
        int c = carry;
        if (i < NN_NODES) {
            int excl = c + incl - v;
            start[i] = excl;
            cursor[i] = excl;
        }
        __syncthreads();
        if (tid == 0) carry = c + sdata[1023];
        __syncthreads();
    }
    if (tid == 0) start[NN_NODES] = carry;   // = N_EDGES
}

// --------------------------- dst-CSR fill ----------------------------------
__global__ __launch_bounds__(256) void k_fill(const int* __restrict__ esrc,
                                              const int* __restrict__ edst,
                                              const int* __restrict__ zarr,
                                              int* __restrict__ cursor,
                                              int* __restrict__ csr) {
    int e = blockIdx.x * blockDim.x + threadIdx.x;
    if (e >= N_EDGES) return;
    int d = edst[e];
    int s = esrc[e];
    int q = 4 * zarr[s] + zarr[d];
    int p = atomicAdd(&cursor[d], 1);
    csr[p] = s | (q << 16) | ((d & 15) << 20);
}

// ----------------- w2 -> w2p[q][u][jj] transpose (cT absorbed) -------------
__global__ __launch_bounds__(256) void k_wprep(const float* __restrict__ w2,
                                               float* __restrict__ w2p) {
    const float cT0f =  0.02830690f;
    const float cT1f = -0.02635231f;
    const float cT2f = -0.01634300f;
    const float cT3f =  0.01265893f;
    const float cT4f =  0.02041241f;
    int idx = blockIdx.x * 256 + threadIdx.x;    // (q*64+u)*64+jj
    if (idx >= 16 * 64 * 64) return;
    int jj = idx & 63;
    int u  = (idx >> 6) & 63;
    int q  = idx >> 12;
    float v = 0.f;
    if (jj < 6) {
        v = cT0f * w2[(u * 16 + q) * 6 + jj];
    } else if (jj < 9) {
        if (u < 24) v = cT1f * w2[6144 + u * 16 + q];
    } else if (jj < 27) {
        int w = (jj - 9) % 6;
        if (u < 24) v = cT2f * w2[6528 + (u * 16 + q) * 6 + w];
    } else if (jj < 57) {
        int w = (jj - 27) % 6;
        if (u < 16) v = cT3f * w2[8832 + (u * 16 + q) * 6 + w];
    } else if (jj < 62) {
        if (u < 16) v = cT4f * w2[10368 + u * 16 + q];
    }
    w2p[idx] = v;
}

// ------------------- node_sh: edge-parallel, 16 nodes/block ----------------
__global__ __launch_bounds__(256) void k_nodesh(const float4* __restrict__ pos4,
                                                const int* __restrict__ start,
                                                const int* __restrict__ csr,
                                                float* __restrict__ node_sh) {
    __shared__ float ns[16][12];
    int t = threadIdx.x;
    if (t < 192) ns[t / 12][t % 12] = 0.f;
    __syncthreads();
    int nbase = blockIdx.x * 16;
    int e0 = start[nbase], e1 = start[nbase + 16];
    for (int idx = e0 + t; idx < e1; idx += 256) {
        int pk = csr[idx];
        int s = pk & 0xFFFF;
        int r = (pk >> 20) & 15;
        float4 pd = pos4[nbase + r];
        float4 ps = pos4[s];
        float x = ps.x - pd.x;
        float y = ps.y - pd.y;
        float z = ps.z - pd.z;
        float B1[3], B2[5];
        sh_from_vec(x, y, z, B1, B2);
        float* nr = &ns[r][0];
        atomicAdd(nr + 0, 1.f);
        atomicAdd(nr + 1, B1[0]); atomicAdd(nr + 2, B1[1]); atomicAdd(nr + 3, B1[2]);
        atomicAdd(nr + 4, B2[0]); atomicAdd(nr + 5, B2[1]); atomicAdd(nr + 6, B2[2]);
        atomicAdd(nr + 7, B2[3]); atomicAdd(nr + 8, B2[4]);
    }
    __syncthreads();
    if (t < 144) {
        int r = t / 9, c = t % 9;
        const float inv_nn = 0.57735026918962576f;
        node_sh[(size_t)(nbase + r) * 12 + c] = ns[r][c] * inv_nn;
    }
}

// ------- fused TP1 -> mid (LDS) -> TP2 tables; Gl[8][4][51] ----------------
__global__ __launch_bounds__(512, 6) void k_mid(const float4* __restrict__ pos4,
                                                const float* __restrict__ node_sh,
                                                const int* __restrict__ start,
                                                const int* __restrict__ csr,
                                                const float* __restrict__ w1,
                                                const int* __restrict__ zarr,
                                                const float* __restrict__ w2p,
                                                float* __restrict__ tab) {
    __shared__ float Gl[8 * 204];          // [r][zs][51]
    __shared__ float smid[8][368];
    __shared__ int szl[8];
    int t = threadIdx.x;
    int nbase = blockIdx.x * 8;
    for (int i = t; i < 8 * 204; i += 512) Gl[i] = 0.f;
    if (t < 8) szl[t] = zarr[nbase + t];
    __syncthreads();

    int e0 = start[nbase], e1 = start[nbase + 8];

    const float r3  = 0.57735026918962576f;
    const float r5  = 0.44721359549995794f;
    const float r6  = 0.40824829046386302f;
    const float r10 = 0.31622776601683794f;
    const float s30 = 0.18257418583505536f;
    const float rt3 = 1.7320508075688772f;
    const float c222 = 0.58554004376911990f;
    const float q6 = 0.40824829046386302f;
    const float h6 = 0.20412414523193151f;
    const float h2 = 0.35355339059327376f;
    const float r2c = 0.70710678118654752f;

    for (int idx = e0 + t; idx < e1; idx += 512) {
        int pk = csr[idx];
        int s = pk & 0xFFFF;
        int zs = (pk >> 18) & 3;           // q>>2 = z_src
        int r = (pk >> 20) & 7;
        float4 pd = pos4[nbase + r];
        float4 ps = pos4[s];
        float x = ps.x - pd.x;
        float y = ps.y - pd.y;
        float z = ps.z - pd.z;
        float B1[3], B2[5];
        sh_from_vec(x, y, z, B1, B2);
        const float4 nv0 = *(const float4*)(node_sh + s * 12);
        const float4 nv1 = *(const float4*)(node_sh + s * 12 + 4);
        float a0 = nv0.x;
        float A1[3] = {nv0.y, nv0.z, nv0.w};
        float A2[5] = {nv1.x, nv1.y, nv1.z, nv1.w, node_sh[s * 12 + 8]};
        float* gr = Gl + r * 204 + zs * 51;

        atomicAdd(gr + 0, a0);
        atomicAdd(gr + 1, a0 * B1[0] * r3);
        atomicAdd(gr + 2, a0 * B1[1] * r3);
        atomicAdd(gr + 3, a0 * B1[2] * r3);
        atomicAdd(gr + 4, a0 * B2[0] * r5);
        atomicAdd(gr + 5, a0 * B2[1] * r5);
        atomicAdd(gr + 6, a0 * B2[2] * r5);
        atomicAdd(gr + 7, a0 * B2[3] * r5);
        atomicAdd(gr + 8, a0 * B2[4] * r5);
        atomicAdd(gr + 9,  A1[0] * r3);
        atomicAdd(gr + 10, A1[1] * r3);
        atomicAdd(gr + 11, A1[2] * r3);
        atomicAdd(gr + 12, -r3 * (A1[0] * B1[0] + A1[1] * B1[1] + A1[2] * B1[2]));
        atomicAdd(gr + 13, -r6 * (A1[1] * B1[2] - A1[2] * B1[1]));
        atomicAdd(gr + 14, -r6 * (A1[2] * B1[0] - A1[0] * B1[2]));
        atomicAdd(gr + 15, -r6 * (A1[0] * B1[1] - A1[1] * B1[0]));
        atomicAdd(gr + 16, r10 * (A1[0] * B1[2] + A1[2] * B1[0]));
        atomicAdd(gr + 17, r10 * (A1[0] * B1[1] + A1[1] * B1[0]));
        atomicAdd(gr + 18, s30 * (2.f * A1[1] * B1[1] - A1[0] * B1[0] - A1[2] * B1[2]));
        atomicAdd(gr + 19, r10 * (A1[1] * B1[2] + A1[2] * B1[1]));
        atomicAdd(gr + 20, r10 * (A1[2] * B1[2] - A1[0] * B1[0]));
        {
            float Byy = -B2[2] * q6 - B2[4] * r2c;
            float Bzz = 2.f * B2[2] * q6;
            float Bxx = -B2[2] * q6 + B2[4] * r2c;
            float Bxy = B2[0] * r2c;
            float Byz = B2[1] * r2c;
            float Bxz = B2[3] * r2c;
            atomicAdd(gr + 21, -r5 * (Byy * A1[0] + Byz * A1[1] + Bxy * A1[2]));
            atomicAdd(gr + 22, -r5 * (Byz * A1[0] + Bzz * A1[1] + Bxz * A1[2]));
            atomicAdd(gr + 23, -r5 * (Bxy * A1[0] + Bxz * A1[1] + Bxx * A1[2]));
        }
        atomicAdd(gr + 24, -s30 * (B2[1] * A1[0] - B2[3] * A1[2] + 2.f * B2[4] * A1[1]));
        atomicAdd(gr + 25, -s30 * (-B2[0] * A1[0] - rt3 * B2[2] * A1[2] + B2[3] * A1[1] - B2[4] * A1[2]));
        atomicAdd(gr + 26, -s30 * (rt3 * B2[1] * A1[2] - rt3 * B2[3] * A1[0]));
        atomicAdd(gr + 27, -s30 * (B2[0] * A1[2] - B2[1] * A1[1] + rt3 * B2[2] * A1[0] - B2[4] * A1[0]));
        atomicAdd(gr + 28, -s30 * (-2.f * B2[0] * A1[1] + B2[1] * A1[2] + B2[3] * A1[0]));
        atomicAdd(gr + 29, A2[0] * r5);
        atomicAdd(gr + 30, A2[1] * r5);
        atomicAdd(gr + 31, A2[2] * r5);
        atomicAdd(gr + 32, A2[3] * r5);
        atomicAdd(gr + 33, A2[4] * r5);
        {
            float Ayy = -A2[2] * q6 - A2[4] * r2c;
            float Azz = 2.f * A2[2] * q6;
            float Axx = -A2[2] * q6 + A2[4] * r2c;
            float Axy = A2[0] * r2c;
            float Ayz = A2[1] * r2c;
            float Axz = A2[3] * r2c;
            atomicAdd(gr + 34, -r5 * (Ayy * B1[0] + Ayz * B1[1] + Axy * B1[2]));
            atomicAdd(gr + 35, -r5 * (Ayz * B1[0] + Azz * B1[1] + Axz * B1[2]));
            atomicAdd(gr + 36, -r5 * (Axy * B1[0] + Axz * B1[1] + Axx * B1[2]));
        }
        atomicAdd(gr + 37, s30 * (A2[1] * B1[0] - A2[3] * B1[2] + 2.f * A2[4] * B1[1]));
        atomicAdd(gr + 38, s30 * (-A2[0] * B1[0] - rt3 * A2[2] * B1[2] + A2[3] * B1[1] - A2[4] * B1[2]));
        atomicAdd(gr + 39, s30 * (rt3 * A2[1] * B1[2] - rt3 * A2[3] * B1[0]));
        atomicAdd(gr + 40, s30 * (A2[0] * B1[2] - A2[1] * B1[1] + rt3 * A2[2] * B1[0] - A2[4] * B1[0]));
        atomicAdd(gr + 41, s30 * (-2.f * A2[0] * B1[1] + A2[1] * B1[2] + A2[3] * B1[0]));
        atomicAdd(gr + 42, r5 * (A2[0] * B2[0] + A2[1] * B2[1] + A2[2] * B2[2] +
                                 A2[3] * B2[3] + A2[4] * B2[4]));
        atomicAdd(gr + 43, s30 * (-A2[0] * B2[1] + A2[1] * B2[0] +
                                  rt3 * (A2[2] * B2[3] - A2[3] * B2[2]) +
                                  A2[3] * B2[4] - A2[4] * B2[3]));
        atomicAdd(gr + 44, s30 * (-2.f * A2[0] * B2[4] + 2.f * A2[4] * B2[0] -
                                  A2[1] * B2[3] + A2[3] * B2[1]));
        atomicAdd(gr + 45, s30 * (A2[0] * B2[3] - A2[3] * B2[0] +
                                  rt3 * (A2[1] * B2[2] - A2[2] * B2[1]) +
                                  A2[1] * B2[4] - A2[4] * B2[1]));
        atomicAdd(gr + 46, -c222 * (-q6 * (A2[0] * B2[2] + A2[2] * B2[0]) +
                                    h2 * (A2[1] * B2[3] + A2[3] * B2[1])));
        atomicAdd(gr + 47, -c222 * (h6 * (A2[1] * B2[2] + A2[2] * B2[1]) -
                                    h2 * (A2[1] * B2[4] + A2[4] * B2[1]) +
                                    h2 * (A2[0] * B2[3] + A2[3] * B2[0])));
        atomicAdd(gr + 48, -c222 * (q6 * (A2[2] * B2[2] - A2[0] * B2[0] - A2[4] * B2[4]) +
                                    h6 * (A2[1] * B2[1] + A2[3] * B2[3])));
        atomicAdd(gr + 49, -c222 * (h6 * (A2[3] * B2[2] + A2[2] * B2[3]) +
                                    h2 * (A2[3] * B2[4] + A2[4] * B2[3]) +
                                    h2 * (A2[0] * B2[1] + A2[1] * B2[0])));
        atomicAdd(gr + 50, -c222 * (-q6 * (A2[4] * B2[2] + A2[2] * B2[4]) +
                                    h2 * (A2[3] * B2[3] - A2[1] * B2[1])));
    }
    __syncthreads();

    // readfirstlane'd z per node -> scalar branches in phase 2.
    int zrs[8];
#pragma unroll
    for (int r2 = 0; r2 < 8; r2++)
        zrs[r2] = __builtin_amdgcn_readfirstlane(szl[r2]);

    // Phase 2: q-loop with shared w1 loads; G-read+FMA only when z_r==q&3.
    int j = t;
    if (j < 368) {
        float acc[8] = {0.f, 0.f, 0.f, 0.f, 0.f, 0.f, 0.f, 0.f};
        if (j < 64) {
            int w = j;
            for (int q = 0; q < 16; q++) {
                float wa = w1[q * 64 + w];
                float wb = w1[2048 + q * 64 + w];
                float wc = w1[5248 + q * 64 + w];
                int zdq = q & 3;
                const float* Gq = Gl + (q >> 2) * 51;
#pragma unroll
                for (int r2 = 0; r2 < 8; r2++) {
                    if (zrs[r2] == zdq) {
                        const float* gq = Gq + r2 * 204;
                        acc[r2] += gq[0] * wa + gq[12] * wb + gq[42] * wc;
                    }
                }
            }
#pragma unroll
            for (int r2 = 0; r2 < 8; r2++) smid[r2][j] = 0.33333333333333333f * acc[r2];
        } else if (j < 136) {
            int tt = j - 64, w = tt / 3, k = tt - 3 * w;
            for (int q = 0; q < 16; q++) {
                float wa = w1[3072 + q * 24 + w];
                float wb = w1[6272 + q * 24 + w];
                int zdq = q & 3;
                const float* Gq = Gl + (q >> 2) * 51;
#pragma unroll
                for (int r2 = 0; r2 < 8; r2++) {
                    if (zrs[r2] == zdq) {
                        const float* gq = Gq + r2 * 204;
                        acc[r2] += gq[13 + k] * wa + gq[43 + k] * wb;
                    }
                }
            }
#pragma unroll
            for (int r2 = 0; r2 < 8; r2++) smid[r2][j] = 0.70710678118654752f * acc[r2];
        } else if (j < 208) {
            int tt = j - 136, w = tt / 3, k = tt - 3 * w;
            for (int q = 0; q < 16; q++) {
                float wa = w1[1024 + q * 24 + w];
                float wb = w1[1664 + q * 24 + w];
                float wc = w1[3712 + q * 24 + w];
                float wd = w1[4608 + q * 24 + w];
                int zdq = q & 3;
                const float* Gq = Gl + (q >> 2) * 51;
#pragma unroll
                for (int r2 = 0; r2 < 8; r2++) {
                    if (zrs[r2] == zdq) {
                        const float* gq = Gq + r2 * 204;
                        acc[r2] += gq[1 + k] * wa + gq[9 + k] * wb +
                                   gq[21 + k] * wc + gq[34 + k] * wd;
                    }
                }
            }
#pragma unroll
            for (int r2 = 0; r2 < 8; r2++) smid[r2][j] = 0.5f * acc[r2];
        } else if (j < 288) {
            int tt = j - 208, w = tt / 5, k = tt - 5 * w;
            for (int q = 0; q < 16; q++) {
                float wa = w1[1408 + q * 16 + w];
                float wb = w1[3456 + q * 16 + w];
                float wc = w1[4352 + q * 16 + w];
                float wd = w1[6656 + q * 16 + w];
                int zdq = q & 3;
                const float* Gq = Gl + (q >> 2) * 51;
#pragma unroll
                for (int r2 = 0; r2 < 8; r2++) {
                    if (zrs[r2] == zdq) {
                        const float* gq = Gq + r2 * 204;
                        acc[r2] += gq[4 + k] * wa + gq[16 + k] * wb +
                                   gq[29 + k] * wc + gq[46 + k] * wd;
                    }
                }
            }
#pragma unroll
            for (int r2 = 0; r2 < 8; r2++) smid[r2][j] = 0.64549722436790280f * acc[r2];
        } else {
            int tt = j - 288, w = tt / 5, k = tt - 5 * w;
            for (int q = 0; q < 16; q++) {
                float wa = w1[4096 + q * 16 + w];
                float wb = w1[4992 + q * 16 + w];
                int zdq = q & 3;
                const float* Gq = Gl + (q >> 2) * 51;
#pragma unroll
                for (int r2 = 0; r2 < 8; r2++) {
                    if (zrs[r2] == zdq) {
                        const float* gq = Gq + r2 * 204;
                        acc[r2] += gq[24 + k] * wa + gq[37 + k] * wb;
                    }
                }
            }
#pragma unroll
            for (int r2 = 0; r2 < 8; r2++) smid[r2][j] = 0.91287092917527690f * acc[r2];
        }
    }
    __syncthreads();

    // Phase 3: wave-per-node, lane = jj; coalesced w2p[q][u][lane] loads.
    {
        int wave = t >> 6;
        int lane = t & 63;
        int r = wave;
        int mbase, mstride, ulim;
        if (lane < 6)       { mbase = 0;                mstride = 1; ulim = 64; }
        else if (lane < 9)  { mbase = 64 + (lane - 6);  mstride = 3; ulim = 24; }
        else if (lane < 27) { mbase = 136 + (lane - 9) / 6;  mstride = 3; ulim = 24; }
        else if (lane < 57) { mbase = 208 + (lane - 27) / 6; mstride = 5; ulim = 16; }
        else if (lane < 62) { mbase = 288 + (lane - 57);     mstride = 5; ulim = 16; }
        else                { mbase = 0;                mstride = 0; ulim = 1; }
        int ulim1 = ulim - 1;
        const float* mr = &smid[r][0];
        int zs = zrs[r];
        for (int zd = 0; zd < 4; zd++) {
            int q = 4 * zs + zd;
            const float* wp = w2p + (size_t)q * 4096 + lane;
            float s0 = 0.f, s1 = 0.f;
#pragma unroll 8
            for (int u = 0; u < 64; u += 2) {
                int um0 = (u < ulim) ? u : ulim1;
                int um1 = (u + 1 < ulim) ? u + 1 : ulim1;
                s0 += mr[mbase + mstride * um0] * wp[u * 64];
                s1 += mr[mbase + mstride * um1] * wp[(u + 1) * 64];
            }
            tab[((size_t)(nbase + r) * 4 + zd) * 64 + lane] = s0 + s1;
        }
    }
}

// ---------------- TP2 + graph reduce: dst-major over tables ----------------
__global__ __launch_bounds__(512, 8) void k_out(const float4* __restrict__ pos4,
                                                const int* __restrict__ zarr,
                                                const int* __restrict__ batch,
                                                const int* __restrict__ start,
                                                const int* __restrict__ csr,
                                                const float* __restrict__ tab,
                                                float* __restrict__ out) {
    int wave = threadIdx.x >> 6;
    int lane = threadIdx.x & 63;
    int n = blockIdx.x * 8 + wave;       // dst node
    float4 pd = pos4[n];
    int zd = zarr[n];
    int s0 = start[n], s1 = start[n + 1];

    int fsel, oidx;
    if (lane < 6)       { fsel = 0;                  oidx = lane + 1; }
    else if (lane < 9)  { fsel = 1 + (lane - 6);     oidx = 0; }
    else if (lane < 27) { fsel = 1 + (lane - 9) / 6; oidx = (lane - 9) % 6 + 1; }
    else if (lane < 57) { fsel = 4 + (lane - 27) / 6; oidx = (lane - 27) % 6 + 1; }
    else if (lane < 62) { fsel = 4 + (lane - 57);    oidx = 0; }
    else                { fsel = -1;                 oidx = 7; }
    float f0 = (fsel == 0) ? 1.f : 0.f;
    float f1 = (fsel == 1) ? 1.f : 0.f;
    float f2 = (fsel == 2) ? 1.f : 0.f;
    float f3 = (fsel == 3) ? 1.f : 0.f;
    float f4 = (fsel == 4) ? 1.f : 0.f;
    float f5 = (fsel == 5) ? 1.f : 0.f;
    float f6 = (fsel == 6) ? 1.f : 0.f;
    float f7 = (fsel == 7) ? 1.f : 0.f;
    float f8 = (fsel == 8) ? 1.f : 0.f;

    float acc = 0.f;
    for (int idx = s0; idx < s1; ++idx) {
        int pk = csr[idx];
        pk = __builtin_amdgcn_readfirstlane(pk);
        int s = pk & 0xFFFF;
        float T = tab[((size_t)s * 4 + zd) * 64 + lane];   // coalesced 256B
        float4 ps = pos4[s];                               // uniform -> scalar
        float x = ps.x - pd.x;
        float y = ps.y - pd.y;
        float z = ps.z - pd.z;
        float B1[3], B2[5];
        sh_from_vec(x, y, z, B1, B2);
        float factor = f0 + f1 * B1[0] + f2 * B1[1] + f3 * B1[2]
                     + f4 * B2[0] + f5 * B2[1] + f6 * B2[2]
                     + f7 * B2[3] + f8 * B2[4];
        acc += T * factor;
    }

    float ov[7];
#pragma unroll
    for (int w = 0; w < 7; w++) ov[w] = (oidx == w) ? acc : 0.f;
#pragma unroll
    for (int off = 32; off > 0; off >>= 1)
#pragma unroll
        for (int w = 0; w < 7; w++) ov[w] += __shfl_down(ov[w], off, 64);
    if (lane == 0) {
        float* og = out + batch[n] * 7;
#pragma unroll
        for (int w = 0; w < 7; w++) atomicAdd(og + w, ov[w]);
    }
}

// ---------------------------------------------------------------------------
extern "C" void kernel_launch(void* const* d_in, const int* in_sizes, int n_in,
                              void* d_out, int out_size, void* d_ws, size_t ws_size,
                              hipStream_t stream) {
    const float* pos  = (const float*)d_in[0];
    const int*   z    = (const int*)d_in[1];
    const int*   bat  = (const int*)d_in[2];
    const int*   esrc = (const int*)d_in[3];
    const int*   edst = (const int*)d_in[4];
    const float* w1   = (const float*)d_in[5];
    const float* w2   = (const float*)d_in[6];
    float* out = (float*)d_out;

    int*   wsI = (int*)d_ws;
    float* wsF = (float*)d_ws;
    int* counts  = wsI + 0;
    int* start   = wsI + 32768;
    int* cursor  = wsI + 65536;
    int* csr     = wsI + 98304;
    float4* pos4   = (float4*)(wsF + 425984);
    float* node_sh = wsF + 524288;
    float* w2p     = wsF + 786432;
    float* tab     = wsF + 1048576;

    k_zero<<<64, 256, 0, stream>>>(pos, counts, out, pos4);
    k_hist<<<(N_EDGES + 255) / 256, 256, 0, stream>>>(edst, counts);
    k_scan<<<1, 1024, 0, stream>>>(counts, start, cursor);
    k_fill<<<(N_EDGES + 255) / 256, 256, 0, stream>>>(esrc, edst, z, cursor, csr);
    k_wprep<<<256, 256, 0, stream>>>(w2, w2p);
    k_nodesh<<<NN_NODES / 16, 256, 0, stream>>>(pos4, start, csr, node_sh);
    k_mid<<<NN_NODES / 8, 512, 0, stream>>>(pos4, node_sh, start, csr, w1, z, w2p, tab);
    k_out<<<NN_NODES / 8, 512, 0, stream>>>(pos4, z, bat, start, csr, tab, out);
}